// Round 1
// baseline (1278.182 us; speedup 1.0000x reference)
//
#include <hip/hip_runtime.h>
#include <math.h>

#define BB 8
#define LL 160000
#define CC 4
#define NFFT 320
#define HOP 160
#define FB 161          // rfft bins
#define TT 1001         // frames
#define KSPAN 16        // 0.05^16 ~ 1.5e-21: exact in fp32
#define PI_D 3.14159265358979323846

__device__ __forceinline__ float2 cmulf(float2 a, float2 b){           // a*b
    return make_float2(a.x*b.x - a.y*b.y, a.x*b.y + a.y*b.x);
}
__device__ __forceinline__ float2 cmulcj(float2 a, float2 b){          // a*conj(b)
    return make_float2(a.x*b.x + a.y*b.y, a.y*b.x - a.x*b.y);
}
__device__ __forceinline__ float2 cjmul(float2 a, float2 b){           // conj(a)*b
    return make_float2(a.x*b.x + a.y*b.y, a.x*b.y - a.y*b.x);
}
__device__ __forceinline__ float2 csub(float2 a, float2 b){ return make_float2(a.x-b.x, a.y-b.y); }
__device__ __forceinline__ float2 cscale(float2 a, float s){ return make_float2(a.x*s, a.y*s); }
__device__ __forceinline__ float2 cdivf(float2 a, float2 b){           // a/b
    float inv = 1.0f/(b.x*b.x + b.y*b.y);
    return make_float2((a.x*b.x + a.y*b.y)*inv, (a.y*b.x - a.x*b.y)*inv);
}

// ---------- steering table: htab[m][k][c] = exp(i*sgn_m*coef*k*c), fp64 then cast (matches ref) ----------
__global__ void k_htab(float* __restrict__ htab){
    int i = blockIdx.x*blockDim.x + threadIdx.x;
    if (i >= 2*FB*CC) return;
    int c = i & 3;
    int k = (i >> 2) % FB;
    int m = i / (FB*CC);
    double coef = 2.0*PI_D*50.0*0.027*sin(40.0*PI_D/180.0)/340.0;
    double sgn = (m == 0) ? -1.0 : 1.0;   // beam 0 = -40 deg, beam 1 = +40 deg
    double ph = sgn*coef*(double)k*(double)c;
    double s, c2;
    sincos(ph, &s, &c2);
    ((float2*)htab)[i] = make_float2((float)c2, (float)s);
}

// ---------- per-(b,c) mean over L ----------
__global__ void k_mean(const float* __restrict__ in, float* __restrict__ mean){
    __shared__ float sm[256];
    int b = blockIdx.x, tid = threadIdx.x;
    const float* p = in + (size_t)b*LL*CC;
    float s = 0.f;
    for (int j = tid; j < LL*CC; j += 256) s += p[j];   // j%4 == tid%4 (channel fixed per thread)
    sm[tid] = s; __syncthreads();
    for (int st = 128; st >= 4; st >>= 1){ if (tid < st) sm[tid] += sm[tid+st]; __syncthreads(); }
    if (tid < 4) mean[b*4 + tid] = sm[tid] * (1.0f/LL);
}

// ---------- per-b max|x - mean| over (L,C) -> 1/max ----------
__global__ void k_maxabs(const float* __restrict__ in, const float* __restrict__ mean,
                         float* __restrict__ invmax){
    __shared__ float sm[256];
    int b = blockIdx.x, tid = threadIdx.x;
    const float* p = in + (size_t)b*LL*CC;
    float mc = mean[b*4 + (tid & 3)];
    float mx = 0.f;
    for (int j = tid; j < LL*CC; j += 256) mx = fmaxf(mx, fabsf(p[j] - mc));
    sm[tid] = mx; __syncthreads();
    for (int st = 128; st >= 4; st >>= 1){ if (tid < st) sm[tid] = fmaxf(sm[tid], sm[tid+st]); __syncthreads(); }
    if (tid == 0) invmax[b] = 1.0f / fmaxf(fmaxf(sm[0], sm[1]), fmaxf(sm[2], sm[3]));
}

// ---------- STFT: direct DFT, 8-frame tile per block, 4 channels packed in float4 ----------
// S layout: complex S[b][k][t][c], c fastest (float4-pair per (b,k,t))
__global__ __launch_bounds__(256) void k_stft(const float* __restrict__ in, const float* __restrict__ win,
                      const float* __restrict__ mean, const float* __restrict__ invmax,
                      float* __restrict__ S){
    __shared__ float wx[8*NFFT*CC];     // [fi][n][c] -> float4 per (fi,n); 40 KB
    __shared__ float lwin[NFFT];
    __shared__ float lmean[4];
    __shared__ float linv;
    int bx = blockIdx.x;
    int b = bx / 126, tile = bx % 126;
    int t0 = tile*8;
    int tid = threadIdx.x;
    for (int i = tid; i < NFFT; i += 256) lwin[i] = win[i];
    if (tid < 4) lmean[tid] = mean[b*4 + tid];
    if (tid == 4) linv = invmax[b];
    __syncthreads();
    const float* px = in + (size_t)b*LL*CC;
    for (int i = tid; i < 8*NFFT*CC; i += 256){
        int fi = i / (NFFT*CC);
        int r  = i % (NFFT*CC);
        int n = r >> 2, c = r & 3;
        int t = t0 + fi;
        if (t < TT){
            int p = t*HOP + n - HOP;                       // reflect-padded position
            int m2 = p < 0 ? -p : (p >= LL ? 2*LL - 2 - p : p);
            wx[i] = (px[(size_t)m2*CC + c] - lmean[c]) * linv * lwin[n];
        }
    }
    __syncthreads();
    const float4* wx4 = (const float4*)wx;
    for (int o = tid; o < 8*FB; o += 256){
        int fi = o / FB, k = o % FB;
        int t = t0 + fi;
        if (t >= TT) continue;
        float sa, ca;
        sincosf(-2.0f*(float)PI_D*(float)k/(float)NFFT, &sa, &ca);
        float2 rot = make_float2(ca, sa);
        float2 cur = make_float2(1.f, 0.f);
        float2 a0 = make_float2(0.f,0.f), a1 = a0, a2 = a0, a3 = a0;
        int base = fi*NFFT;
        for (int n = 0; n < NFFT; ++n){
            float4 w4 = wx4[base + n];                     // LDS broadcast (same addr all lanes)
            a0.x += w4.x*cur.x; a0.y += w4.x*cur.y;
            a1.x += w4.y*cur.x; a1.y += w4.y*cur.y;
            a2.x += w4.z*cur.x; a2.y += w4.z*cur.y;
            a3.x += w4.w*cur.x; a3.y += w4.w*cur.y;
            cur = cmulf(cur, rot);
        }
        size_t idx = ((size_t)(b*FB + k)*TT + t)*2;        // float4 units
        float4* S4 = (float4*)S;
        S4[idx]   = make_float4(a0.x, a0.y, a1.x, a1.y);
        S4[idx+1] = make_float4(a2.x, a2.y, a3.x, a3.y);
    }
}

// ---------- scan replaced by truncated exponential sum + Cholesky solve + beamform ----------
// S1/S2 layout: complex [b][f][t]
__global__ __launch_bounds__(256) void k_scan(const float* __restrict__ S, const float* __restrict__ htab,
                      float* __restrict__ S1, float* __restrict__ S2){
    int o = blockIdx.x*256 + threadIdx.x;
    if (o >= BB*FB*TT) return;
    int t  = o % TT;
    int bf = o / TT;               // b*FB + f
    int f  = bf % FB;
    const float4* Sp = (const float4*)S;
    size_t base4 = (size_t)bf*TT*2;
    float d0=0,d1=0,d2=0,d3=0;
    float2 r10={0,0}, r20={0,0}, r30={0,0}, r21={0,0}, r31={0,0}, r32={0,0};
    float2 X0={0,0}, X1={0,0}, X2={0,0}, X3={0,0};
    int tau0 = t - (KSPAN-1); if (tau0 < 0) tau0 = 0;
    float w = 0.95f;
    for (int tau = t; tau >= tau0; --tau){
        float4 v0 = Sp[base4 + (size_t)tau*2];
        float4 v1 = Sp[base4 + (size_t)tau*2 + 1];
        float2 x0 = make_float2(v0.x, v0.y), x1 = make_float2(v0.z, v0.w);
        float2 x2 = make_float2(v1.x, v1.y), x3 = make_float2(v1.z, v1.w);
        if (tau == t){ X0=x0; X1=x1; X2=x2; X3=x3; }
        // weight(tau): 0.95*0.05^(t-tau), except tau==0 gets 0.05^t (first-frame init)
        float wt = (tau == 0) ? w*(1.0f/0.95f) : w;
        float y0x=wt*x0.x, y0y=wt*x0.y, y1x=wt*x1.x, y1y=wt*x1.y;
        float y2x=wt*x2.x, y2y=wt*x2.y, y3x=wt*x3.x, y3y=wt*x3.y;
        d0 += y0x*x0.x + y0y*x0.y;
        d1 += y1x*x1.x + y1y*x1.y;
        d2 += y2x*x2.x + y2y*x2.y;
        d3 += y3x*x3.x + y3y*x3.y;
        r10.x += y1x*x0.x + y1y*x0.y;  r10.y += y1y*x0.x - y1x*x0.y;
        r20.x += y2x*x0.x + y2y*x0.y;  r20.y += y2y*x0.x - y2x*x0.y;
        r30.x += y3x*x0.x + y3y*x0.y;  r30.y += y3y*x0.x - y3x*x0.y;
        r21.x += y2x*x1.x + y2y*x1.y;  r21.y += y2y*x1.x - y2x*x1.y;
        r31.x += y3x*x1.x + y3y*x1.y;  r31.y += y3y*x1.x - y3x*x1.y;
        r32.x += y3x*x2.x + y3y*x2.y;  r32.y += y3y*x2.x - y3x*x2.y;
        w *= 0.05f;
    }
    float tr  = d0 + d1 + d2 + d3;
    float lam = tr * 0.25f;
    float a00 = d0 + lam, a11 = d1 + lam, a22 = d2 + lam, a33 = d3 + lam;
    // Cholesky of Hermitian PD 4x4 (lower)
    float l00 = sqrtf(a00);                       float i00 = 1.0f/l00;
    float2 L10 = cscale(r10, i00);
    float2 L20 = cscale(r20, i00);
    float2 L30 = cscale(r30, i00);
    float l11 = sqrtf(a11 - (L10.x*L10.x + L10.y*L10.y));                 float i11 = 1.0f/l11;
    float2 L21 = cscale(csub(r21, cmulcj(L20, L10)), i11);
    float2 L31 = cscale(csub(r31, cmulcj(L30, L10)), i11);
    float l22 = sqrtf(a22 - (L20.x*L20.x+L20.y*L20.y) - (L21.x*L21.x+L21.y*L21.y)); float i22 = 1.0f/l22;
    float2 L32 = cscale(csub(csub(r32, cmulcj(L30, L20)), cmulcj(L31, L21)), i22);
    float l33 = sqrtf(a33 - (L30.x*L30.x+L30.y*L30.y) - (L31.x*L31.x+L31.y*L31.y)
                          - (L32.x*L32.x+L32.y*L32.y));                   float i33 = 1.0f/l33;
    const float2* hp = (const float2*)htab;
    for (int m = 0; m < 2; ++m){
        float2 h0 = hp[(m*FB + f)*4 + 0];
        float2 h1 = hp[(m*FB + f)*4 + 1];
        float2 h2 = hp[(m*FB + f)*4 + 2];
        float2 h3 = hp[(m*FB + f)*4 + 3];
        // forward solve L u = h
        float2 u0 = cscale(h0, i00);
        float2 u1 = cscale(csub(h1, cmulf(L10,u0)), i11);
        float2 u2 = cscale(csub(csub(h2, cmulf(L20,u0)), cmulf(L21,u1)), i22);
        float2 u3 = cscale(csub(csub(csub(h3, cmulf(L30,u0)), cmulf(L31,u1)), cmulf(L32,u2)), i33);
        // back solve L^H y = u
        float2 y3v = cscale(u3, i33);
        float2 y2v = cscale(csub(u2, cjmul(L32, y3v)), i22);
        float2 y1v = cscale(csub(csub(u1, cjmul(L21, y2v)), cjmul(L31, y3v)), i11);
        float2 y0v = cscale(csub(csub(csub(u0, cjmul(L10, y1v)), cjmul(L20, y2v)), cjmul(L30, y3v)), i00);
        // den = h^H y ; num = y^H X ; s = num / conj(den)
        float2 den = cjmul(h0, y0v), tmp;
        tmp = cjmul(h1, y1v); den.x += tmp.x; den.y += tmp.y;
        tmp = cjmul(h2, y2v); den.x += tmp.x; den.y += tmp.y;
        tmp = cjmul(h3, y3v); den.x += tmp.x; den.y += tmp.y;
        float2 num = cjmul(y0v, X0);
        tmp = cjmul(y1v, X1); num.x += tmp.x; num.y += tmp.y;
        tmp = cjmul(y2v, X2); num.x += tmp.x; num.y += tmp.y;
        tmp = cjmul(y3v, X3); num.x += tmp.x; num.y += tmp.y;
        float2 s = cdivf(num, make_float2(den.x, -den.y));
        float* dst = (m == 0) ? S1 : S2;
        ((float2*)dst)[(size_t)bf*TT + t] = s;
    }
}

// ---------- irfft(320) per (beam,b,t), rectangular-window frames ----------
// frames layout: [beam][b][t][n]
__global__ __launch_bounds__(320) void k_irfft(const float* __restrict__ S1, const float* __restrict__ S2,
                       float* __restrict__ frames){
    __shared__ float2 ld[FB];
    int bid = blockIdx.x;                  // (beam*BB + b)*TT + t
    int t  = bid % TT;
    int rb = bid / TT;
    int b  = rb % BB;
    int beam = rb / BB;
    const float2* Sm = (const float2*)((beam == 0) ? S1 : S2);
    int tid = threadIdx.x;
    if (tid < FB) ld[tid] = Sm[(size_t)(b*FB + tid)*TT + t];
    __syncthreads();
    int n = tid;
    float sa, ca;
    sincosf(2.0f*(float)PI_D*(float)n/(float)NFFT, &sa, &ca);
    float2 rot = make_float2(ca, sa);
    float2 cur = rot;
    float acc = 0.f;
    for (int k = 1; k <= 159; ++k){
        float2 X = ld[k];                  // LDS broadcast
        acc += X.x*cur.x - X.y*cur.y;      // Re(X * e^{+i k ang})
        cur = cmulf(cur, rot);
    }
    float v = ld[0].x + ((n & 1) ? -ld[160].x : ld[160].x) + 2.0f*acc;
    frames[(size_t)bid*NFFT + n] = v * (1.0f/NFFT);
}

// ---------- overlap-add (wsum==2 everywhere in cropped interior) ----------
__global__ void k_ola(const float* __restrict__ frames, float* __restrict__ out){
    int gid = blockIdx.x*256 + threadIdx.x;
    if (gid >= 2*BB*LL) return;
    int o  = gid % LL;
    int rb = gid / LL;                     // beam*BB + b
    int i  = o + HOP;                      // position in padded OLA buffer
    int t1 = i / HOP;                      // 1..1000
    int r  = i - t1*HOP;                   // 0..159
    const float* fb = frames + (size_t)rb*TT*NFFT;
    float v = fb[(size_t)t1*NFFT + r] + fb[(size_t)(t1-1)*NFFT + r + HOP];
    out[gid] = v * 0.5f;
}

extern "C" void kernel_launch(void* const* d_in, const int* in_sizes, int n_in,
                              void* d_out, int out_size, void* d_ws, size_t ws_size,
                              hipStream_t stream){
    const float* in  = (const float*)d_in[0];   // [B, L, C] fp32
    const float* win = (const float*)d_in[1];   // [320] fp32
    float* ws = (float*)d_ws;
    // workspace layout (floats): mean 32 | invmax 8 | htab 2576 (pad to 2624) | S1 | S2 | S (frames alias S)
    float* mean   = ws;
    float* invmax = ws + 32;
    float* htab   = ws + 48;
    float* S1     = ws + 2624;
    size_t nS1 = (size_t)2*BB*FB*TT;            // 2,578,576 floats
    float* S2 = S1 + nS1;
    float* S  = S2 + nS1;                       // 10,314,304 floats
    float* frames = S;                          // alias: S dead after k_scan; frames = 5,125,120 floats

    k_htab<<<dim3(6), dim3(256), 0, stream>>>(htab);
    k_mean<<<dim3(BB), dim3(256), 0, stream>>>(in, mean);
    k_maxabs<<<dim3(BB), dim3(256), 0, stream>>>(in, mean, invmax);
    k_stft<<<dim3(BB*126), dim3(256), 0, stream>>>(in, win, mean, invmax, S);
    int ntup = BB*FB*TT;
    k_scan<<<dim3((ntup + 255)/256), dim3(256), 0, stream>>>(S, htab, S1, S2);
    k_irfft<<<dim3(2*BB*TT), dim3(320), 0, stream>>>(S1, S2, frames);
    k_ola<<<dim3((2*BB*LL + 255)/256), dim3(256), 0, stream>>>(frames, (float*)d_out);
}

// Round 2
// 485.972 us; speedup vs baseline: 2.6302x; 2.6302x over previous
//
#include <hip/hip_runtime.h>
#include <math.h>

#define BB 8
#define LL 160000
#define CC 4
#define NFFT 320
#define HOP 160
#define FB 161          // rfft bins
#define TT 1001         // frames
#define KSPAN 16        // 0.05^16 ~ 1.5e-21: exact in fp32
#define RBLK 128        // stats blocks per batch
#define PI_D 3.14159265358979323846

__device__ __forceinline__ float2 cmulf(float2 a, float2 b){           // a*b
    return make_float2(a.x*b.x - a.y*b.y, a.x*b.y + a.y*b.x);
}
__device__ __forceinline__ float2 cmulcj(float2 a, float2 b){          // a*conj(b)
    return make_float2(a.x*b.x + a.y*b.y, a.y*b.x - a.x*b.y);
}
__device__ __forceinline__ float2 cjmul(float2 a, float2 b){           // conj(a)*b
    return make_float2(a.x*b.x + a.y*b.y, a.x*b.y - a.y*b.x);
}
__device__ __forceinline__ float2 csub(float2 a, float2 b){ return make_float2(a.x-b.x, a.y-b.y); }
__device__ __forceinline__ float2 cscale(float2 a, float s){ return make_float2(a.x*s, a.y*s); }
__device__ __forceinline__ float2 cdivf(float2 a, float2 b){           // a/b
    float inv = 1.0f/(b.x*b.x + b.y*b.y);
    return make_float2((a.x*b.x + a.y*b.y)*inv, (a.y*b.x - a.x*b.y)*inv);
}

// ---------- steering table: htab[m][k][c] = exp(i*sgn_m*coef*k*c), fp64 then cast (matches ref) ----------
__global__ void k_htab(float* __restrict__ htab){
    int i = blockIdx.x*blockDim.x + threadIdx.x;
    if (i >= 2*FB*CC) return;
    int c = i & 3;
    int k = (i >> 2) % FB;
    int m = i / (FB*CC);
    double coef = 2.0*PI_D*50.0*0.027*sin(40.0*PI_D/180.0)/340.0;
    double sgn = (m == 0) ? -1.0 : 1.0;   // beam 0 = -40 deg, beam 1 = +40 deg
    double ph = sgn*coef*(double)k*(double)c;
    double s, c2;
    sincos(ph, &s, &c2);
    ((float2*)htab)[i] = make_float2((float)c2, (float)s);
}

// ---------- stage 1: per-(b,chunk) partial {sum4, min4, max4} over L (single pass, float4) ----------
__global__ __launch_bounds__(256) void k_stats1(const float* __restrict__ in, float* __restrict__ part){
    __shared__ float4 s4[256];
    __shared__ float4 mn4[256];
    __shared__ float4 mx4[256];
    int b = blockIdx.x / RBLK, chunk = blockIdx.x % RBLK;
    int tid = threadIdx.x;
    const float4* p = (const float4*)(in + (size_t)b*LL*CC);
    const int per = LL / RBLK;                 // 1250 float4 samples per chunk
    int start = chunk*per;
    float4 s  = make_float4(0.f,0.f,0.f,0.f);
    float4 mn = make_float4( 3.4e38f, 3.4e38f, 3.4e38f, 3.4e38f);
    float4 mx = make_float4(-3.4e38f,-3.4e38f,-3.4e38f,-3.4e38f);
    for (int i = start + tid; i < start + per; i += 256){
        float4 v = p[i];
        s.x += v.x; s.y += v.y; s.z += v.z; s.w += v.w;
        mn.x = fminf(mn.x, v.x); mn.y = fminf(mn.y, v.y); mn.z = fminf(mn.z, v.z); mn.w = fminf(mn.w, v.w);
        mx.x = fmaxf(mx.x, v.x); mx.y = fmaxf(mx.y, v.y); mx.z = fmaxf(mx.z, v.z); mx.w = fmaxf(mx.w, v.w);
    }
    s4[tid] = s; mn4[tid] = mn; mx4[tid] = mx;
    __syncthreads();
    for (int st = 128; st >= 1; st >>= 1){
        if (tid < st){
            float4 a = s4[tid], c = s4[tid+st];
            s4[tid] = make_float4(a.x+c.x, a.y+c.y, a.z+c.z, a.w+c.w);
            float4 d = mn4[tid], e = mn4[tid+st];
            mn4[tid] = make_float4(fminf(d.x,e.x), fminf(d.y,e.y), fminf(d.z,e.z), fminf(d.w,e.w));
            float4 f = mx4[tid], g = mx4[tid+st];
            mx4[tid] = make_float4(fmaxf(f.x,g.x), fmaxf(f.y,g.y), fmaxf(f.z,g.z), fmaxf(f.w,g.w));
        }
        __syncthreads();
    }
    if (tid == 0){
        float* dst = part + (size_t)(b*RBLK + chunk)*12;
        float4 a = s4[0], d = mn4[0], f = mx4[0];
        dst[0]=a.x; dst[1]=a.y; dst[2]=a.z; dst[3]=a.w;
        dst[4]=d.x; dst[5]=d.y; dst[6]=d.z; dst[7]=d.w;
        dst[8]=f.x; dst[9]=f.y; dst[10]=f.z; dst[11]=f.w;
    }
}

// ---------- stage 2: finalize mean + invmax per batch ----------
__global__ __launch_bounds__(128) void k_stats2(const float* __restrict__ part,
                                                float* __restrict__ mean, float* __restrict__ invmax){
    __shared__ float4 s4[128];
    __shared__ float4 mn4[128];
    __shared__ float4 mx4[128];
    int b = blockIdx.x, tid = threadIdx.x;
    const float* src = part + (size_t)(b*RBLK + tid)*12;
    s4[tid]  = make_float4(src[0], src[1], src[2], src[3]);
    mn4[tid] = make_float4(src[4], src[5], src[6], src[7]);
    mx4[tid] = make_float4(src[8], src[9], src[10], src[11]);
    __syncthreads();
    for (int st = 64; st >= 1; st >>= 1){
        if (tid < st){
            float4 a = s4[tid], c = s4[tid+st];
            s4[tid] = make_float4(a.x+c.x, a.y+c.y, a.z+c.z, a.w+c.w);
            float4 d = mn4[tid], e = mn4[tid+st];
            mn4[tid] = make_float4(fminf(d.x,e.x), fminf(d.y,e.y), fminf(d.z,e.z), fminf(d.w,e.w));
            float4 f = mx4[tid], g = mx4[tid+st];
            mx4[tid] = make_float4(fmaxf(f.x,g.x), fmaxf(f.y,g.y), fmaxf(f.z,g.z), fmaxf(f.w,g.w));
        }
        __syncthreads();
    }
    if (tid == 0){
        float4 sum = s4[0], mn = mn4[0], mx = mx4[0];
        float m0 = sum.x*(1.0f/LL), m1 = sum.y*(1.0f/LL), m2 = sum.z*(1.0f/LL), m3 = sum.w*(1.0f/LL);
        mean[b*4+0]=m0; mean[b*4+1]=m1; mean[b*4+2]=m2; mean[b*4+3]=m3;
        // max|x - m| = max(max_x - m, m - min_x), per channel, then over channels
        float a0 = fmaxf(mx.x - m0, m0 - mn.x);
        float a1 = fmaxf(mx.y - m1, m1 - mn.y);
        float a2 = fmaxf(mx.z - m2, m2 - mn.z);
        float a3 = fmaxf(mx.w - m3, m3 - mn.w);
        invmax[b] = 1.0f / fmaxf(fmaxf(a0, a1), fmaxf(a2, a3));
    }
}

// ---------- STFT: direct DFT, 8-frame tile per block, 4 channels packed in float4 ----------
// S layout: complex S[b][k][t][c], c fastest (float4-pair per (b,k,t))
__global__ __launch_bounds__(256) void k_stft(const float* __restrict__ in, const float* __restrict__ win,
                      const float* __restrict__ mean, const float* __restrict__ invmax,
                      float* __restrict__ S){
    __shared__ float wx[8*NFFT*CC];     // [fi][n][c] -> float4 per (fi,n); 40 KB
    __shared__ float lwin[NFFT];
    __shared__ float lmean[4];
    __shared__ float linv;
    int bx = blockIdx.x;
    int b = bx / 126, tile = bx % 126;
    int t0 = tile*8;
    int tid = threadIdx.x;
    for (int i = tid; i < NFFT; i += 256) lwin[i] = win[i];
    if (tid < 4) lmean[tid] = mean[b*4 + tid];
    if (tid == 4) linv = invmax[b];
    __syncthreads();
    const float* px = in + (size_t)b*LL*CC;
    for (int i = tid; i < 8*NFFT*CC; i += 256){
        int fi = i / (NFFT*CC);
        int r  = i % (NFFT*CC);
        int n = r >> 2, c = r & 3;
        int t = t0 + fi;
        if (t < TT){
            int p = t*HOP + n - HOP;                       // reflect-padded position
            int m2 = p < 0 ? -p : (p >= LL ? 2*LL - 2 - p : p);
            wx[i] = (px[(size_t)m2*CC + c] - lmean[c]) * linv * lwin[n];
        }
    }
    __syncthreads();
    const float4* wx4 = (const float4*)wx;
    for (int o = tid; o < 8*FB; o += 256){
        int fi = o / FB, k = o % FB;
        int t = t0 + fi;
        if (t >= TT) continue;
        float sa, ca;
        sincosf(-2.0f*(float)PI_D*(float)k/(float)NFFT, &sa, &ca);
        float2 rot = make_float2(ca, sa);
        float2 cur = make_float2(1.f, 0.f);
        float2 a0 = make_float2(0.f,0.f), a1 = a0, a2 = a0, a3 = a0;
        int base = fi*NFFT;
        for (int n = 0; n < NFFT; ++n){
            float4 w4 = wx4[base + n];                     // LDS broadcast (same addr all lanes)
            a0.x += w4.x*cur.x; a0.y += w4.x*cur.y;
            a1.x += w4.y*cur.x; a1.y += w4.y*cur.y;
            a2.x += w4.z*cur.x; a2.y += w4.z*cur.y;
            a3.x += w4.w*cur.x; a3.y += w4.w*cur.y;
            cur = cmulf(cur, rot);
        }
        size_t idx = ((size_t)(b*FB + k)*TT + t)*2;        // float4 units
        float4* S4 = (float4*)S;
        S4[idx]   = make_float4(a0.x, a0.y, a1.x, a1.y);
        S4[idx+1] = make_float4(a2.x, a2.y, a3.x, a3.y);
    }
}

// ---------- scan replaced by truncated exponential sum + Cholesky solve + beamform ----------
// S1/S2 layout: complex [b][f][t]
__global__ __launch_bounds__(256) void k_scan(const float* __restrict__ S, const float* __restrict__ htab,
                      float* __restrict__ S1, float* __restrict__ S2){
    int o = blockIdx.x*256 + threadIdx.x;
    if (o >= BB*FB*TT) return;
    int t  = o % TT;
    int bf = o / TT;               // b*FB + f
    int f  = bf % FB;
    const float4* Sp = (const float4*)S;
    size_t base4 = (size_t)bf*TT*2;
    float d0=0,d1=0,d2=0,d3=0;
    float2 r10={0,0}, r20={0,0}, r30={0,0}, r21={0,0}, r31={0,0}, r32={0,0};
    float2 X0={0,0}, X1={0,0}, X2={0,0}, X3={0,0};
    int tau0 = t - (KSPAN-1); if (tau0 < 0) tau0 = 0;
    float w = 0.95f;
    for (int tau = t; tau >= tau0; --tau){
        float4 v0 = Sp[base4 + (size_t)tau*2];
        float4 v1 = Sp[base4 + (size_t)tau*2 + 1];
        float2 x0 = make_float2(v0.x, v0.y), x1 = make_float2(v0.z, v0.w);
        float2 x2 = make_float2(v1.x, v1.y), x3 = make_float2(v1.z, v1.w);
        if (tau == t){ X0=x0; X1=x1; X2=x2; X3=x3; }
        // weight(tau): 0.95*0.05^(t-tau), except tau==0 gets 0.05^t (first-frame init)
        float wt = (tau == 0) ? w*(1.0f/0.95f) : w;
        float y0x=wt*x0.x, y0y=wt*x0.y, y1x=wt*x1.x, y1y=wt*x1.y;
        float y2x=wt*x2.x, y2y=wt*x2.y, y3x=wt*x3.x, y3y=wt*x3.y;
        d0 += y0x*x0.x + y0y*x0.y;
        d1 += y1x*x1.x + y1y*x1.y;
        d2 += y2x*x2.x + y2y*x2.y;
        d3 += y3x*x3.x + y3y*x3.y;
        r10.x += y1x*x0.x + y1y*x0.y;  r10.y += y1y*x0.x - y1x*x0.y;
        r20.x += y2x*x0.x + y2y*x0.y;  r20.y += y2y*x0.x - y2x*x0.y;
        r30.x += y3x*x0.x + y3y*x0.y;  r30.y += y3y*x0.x - y3x*x0.y;
        r21.x += y2x*x1.x + y2y*x1.y;  r21.y += y2y*x1.x - y2x*x1.y;
        r31.x += y3x*x1.x + y3y*x1.y;  r31.y += y3y*x1.x - y3x*x1.y;
        r32.x += y3x*x2.x + y3y*x2.y;  r32.y += y3y*x2.x - y3x*x2.y;
        w *= 0.05f;
    }
    float tr  = d0 + d1 + d2 + d3;
    float lam = tr * 0.25f;
    float a00 = d0 + lam, a11 = d1 + lam, a22 = d2 + lam, a33 = d3 + lam;
    // Cholesky of Hermitian PD 4x4 (lower)
    float l00 = sqrtf(a00);                       float i00 = 1.0f/l00;
    float2 L10 = cscale(r10, i00);
    float2 L20 = cscale(r20, i00);
    float2 L30 = cscale(r30, i00);
    float l11 = sqrtf(a11 - (L10.x*L10.x + L10.y*L10.y));                 float i11 = 1.0f/l11;
    float2 L21 = cscale(csub(r21, cmulcj(L20, L10)), i11);
    float2 L31 = cscale(csub(r31, cmulcj(L30, L10)), i11);
    float l22 = sqrtf(a22 - (L20.x*L20.x+L20.y*L20.y) - (L21.x*L21.x+L21.y*L21.y)); float i22 = 1.0f/l22;
    float2 L32 = cscale(csub(csub(r32, cmulcj(L30, L20)), cmulcj(L31, L21)), i22);
    float l33 = sqrtf(a33 - (L30.x*L30.x+L30.y*L30.y) - (L31.x*L31.x+L31.y*L31.y)
                          - (L32.x*L32.x+L32.y*L32.y));                   float i33 = 1.0f/l33;
    const float2* hp = (const float2*)htab;
    for (int m = 0; m < 2; ++m){
        float2 h0 = hp[(m*FB + f)*4 + 0];
        float2 h1 = hp[(m*FB + f)*4 + 1];
        float2 h2 = hp[(m*FB + f)*4 + 2];
        float2 h3 = hp[(m*FB + f)*4 + 3];
        // forward solve L u = h
        float2 u0 = cscale(h0, i00);
        float2 u1 = cscale(csub(h1, cmulf(L10,u0)), i11);
        float2 u2 = cscale(csub(csub(h2, cmulf(L20,u0)), cmulf(L21,u1)), i22);
        float2 u3 = cscale(csub(csub(csub(h3, cmulf(L30,u0)), cmulf(L31,u1)), cmulf(L32,u2)), i33);
        // back solve L^H y = u
        float2 y3v = cscale(u3, i33);
        float2 y2v = cscale(csub(u2, cjmul(L32, y3v)), i22);
        float2 y1v = cscale(csub(csub(u1, cjmul(L21, y2v)), cjmul(L31, y3v)), i11);
        float2 y0v = cscale(csub(csub(csub(u0, cjmul(L10, y1v)), cjmul(L20, y2v)), cjmul(L30, y3v)), i00);
        // den = h^H y ; num = y^H X ; s = num / conj(den)
        float2 den = cjmul(h0, y0v), tmp;
        tmp = cjmul(h1, y1v); den.x += tmp.x; den.y += tmp.y;
        tmp = cjmul(h2, y2v); den.x += tmp.x; den.y += tmp.y;
        tmp = cjmul(h3, y3v); den.x += tmp.x; den.y += tmp.y;
        float2 num = cjmul(y0v, X0);
        tmp = cjmul(y1v, X1); num.x += tmp.x; num.y += tmp.y;
        tmp = cjmul(y2v, X2); num.x += tmp.x; num.y += tmp.y;
        tmp = cjmul(y3v, X3); num.x += tmp.x; num.y += tmp.y;
        float2 s = cdivf(num, make_float2(den.x, -den.y));
        float* dst = (m == 0) ? S1 : S2;
        ((float2*)dst)[(size_t)bf*TT + t] = s;
    }
}

// ---------- irfft(320) per (beam,b,t), rectangular-window frames ----------
// frames layout: [beam][b][t][n]
__global__ __launch_bounds__(320) void k_irfft(const float* __restrict__ S1, const float* __restrict__ S2,
                       float* __restrict__ frames){
    __shared__ float2 ld[FB];
    int bid = blockIdx.x;                  // (beam*BB + b)*TT + t
    int t  = bid % TT;
    int rb = bid / TT;
    int b  = rb % BB;
    int beam = rb / BB;
    const float2* Sm = (const float2*)((beam == 0) ? S1 : S2);
    int tid = threadIdx.x;
    if (tid < FB) ld[tid] = Sm[(size_t)(b*FB + tid)*TT + t];
    __syncthreads();
    int n = tid;
    float sa, ca;
    sincosf(2.0f*(float)PI_D*(float)n/(float)NFFT, &sa, &ca);
    float2 rot = make_float2(ca, sa);
    float2 cur = rot;
    float acc = 0.f;
    for (int k = 1; k <= 159; ++k){
        float2 X = ld[k];                  // LDS broadcast
        acc += X.x*cur.x - X.y*cur.y;      // Re(X * e^{+i k ang})
        cur = cmulf(cur, rot);
    }
    float v = ld[0].x + ((n & 1) ? -ld[160].x : ld[160].x) + 2.0f*acc;
    frames[(size_t)bid*NFFT + n] = v * (1.0f/NFFT);
}

// ---------- overlap-add (wsum==2 everywhere in cropped interior) ----------
__global__ void k_ola(const float* __restrict__ frames, float* __restrict__ out){
    int gid = blockIdx.x*256 + threadIdx.x;
    if (gid >= 2*BB*LL) return;
    int o  = gid % LL;
    int rb = gid / LL;                     // beam*BB + b
    int i  = o + HOP;                      // position in padded OLA buffer
    int t1 = i / HOP;                      // 1..1000
    int r  = i - t1*HOP;                   // 0..159
    const float* fb = frames + (size_t)rb*TT*NFFT;
    float v = fb[(size_t)t1*NFFT + r] + fb[(size_t)(t1-1)*NFFT + r + HOP];
    out[gid] = v * 0.5f;
}

extern "C" void kernel_launch(void* const* d_in, const int* in_sizes, int n_in,
                              void* d_out, int out_size, void* d_ws, size_t ws_size,
                              hipStream_t stream){
    const float* in  = (const float*)d_in[0];   // [B, L, C] fp32
    const float* win = (const float*)d_in[1];   // [320] fp32
    float* ws = (float*)d_ws;
    // workspace layout (floats): mean 32 | invmax 8 | htab 2576 (pad to 2624) | S1 | S2 | S (frames alias S)
    float* mean   = ws;
    float* invmax = ws + 32;
    float* htab   = ws + 48;
    float* S1     = ws + 2624;
    size_t nS1 = (size_t)2*BB*FB*TT;            // 2,578,576 floats
    float* S2 = S1 + nS1;
    float* S  = S2 + nS1;                       // 10,314,304 floats
    float* frames = S;                          // alias: S dead after k_scan; frames = 5,125,120 floats
    float* part = S1;                           // alias: partials (8*128*12 floats) dead before k_scan writes S1

    k_htab<<<dim3(6), dim3(256), 0, stream>>>(htab);
    k_stats1<<<dim3(BB*RBLK), dim3(256), 0, stream>>>(in, part);
    k_stats2<<<dim3(BB), dim3(128), 0, stream>>>(part, mean, invmax);
    k_stft<<<dim3(BB*126), dim3(256), 0, stream>>>(in, win, mean, invmax, S);
    int ntup = BB*FB*TT;
    k_scan<<<dim3((ntup + 255)/256), dim3(256), 0, stream>>>(S, htab, S1, S2);
    k_irfft<<<dim3(2*BB*TT), dim3(320), 0, stream>>>(S1, S2, frames);
    k_ola<<<dim3((2*BB*LL + 255)/256), dim3(256), 0, stream>>>(frames, (float*)d_out);
}

// Round 3
// 369.655 us; speedup vs baseline: 3.4578x; 1.3147x over previous
//
#include <hip/hip_runtime.h>
#include <hip/hip_bf16.h>
#include <math.h>

#define BB 8
#define LL 160000
#define CC 4
#define NFFT 320
#define HOP 160
#define FB 161          // rfft bins
#define TT 1001         // frames
#define KSPAN 16        // 0.05^16 ~ 1.5e-21: exact in fp32
#define RBLK 128        // stats blocks per batch
#define PI_D 3.14159265358979323846

#define GM 16016        // GEMM M = 2*BB*TT rows (beam,b,t)
#define KSEC 352        // padded K per split-section (322 used)
#define LDK 704         // A/Bt leading dim = 2 sections
#define KT 11           // K-tiles of 32 per section

typedef __attribute__((ext_vector_type(8))) short bf16x8;
typedef __attribute__((ext_vector_type(4))) float f32x4;

__device__ __forceinline__ float2 cmulf(float2 a, float2 b){           // a*b
    return make_float2(a.x*b.x - a.y*b.y, a.x*b.y + a.y*b.x);
}
__device__ __forceinline__ float2 cmulcj(float2 a, float2 b){          // a*conj(b)
    return make_float2(a.x*b.x + a.y*b.y, a.y*b.x - a.x*b.y);
}
__device__ __forceinline__ float2 cjmul(float2 a, float2 b){           // conj(a)*b
    return make_float2(a.x*b.x + a.y*b.y, a.x*b.y - a.y*b.x);
}
__device__ __forceinline__ float2 csub(float2 a, float2 b){ return make_float2(a.x-b.x, a.y-b.y); }
__device__ __forceinline__ float2 cscale(float2 a, float s){ return make_float2(a.x*s, a.y*s); }
__device__ __forceinline__ float2 cdivf(float2 a, float2 b){           // a/b
    float inv = 1.0f/(b.x*b.x + b.y*b.y);
    return make_float2((a.x*b.x + a.y*b.y)*inv, (a.y*b.x - a.x*b.y)*inv);
}
__device__ __forceinline__ short bf_hi(float v){
    __hip_bfloat16 h = __float2bfloat16(v);
    short s; __builtin_memcpy(&s, &h, 2); return s;
}
__device__ __forceinline__ short bf_lo(float v){
    __hip_bfloat16 h = __float2bfloat16(v);
    float r = v - __bfloat162float(h);
    __hip_bfloat16 l = __float2bfloat16(r);
    short s; __builtin_memcpy(&s, &l, 2); return s;
}

// ---------- steering table: htab[m][k][c] = exp(i*sgn_m*coef*k*c), fp64 then cast (matches ref) ----------
__global__ void k_htab(float* __restrict__ htab){
    int i = blockIdx.x*blockDim.x + threadIdx.x;
    if (i >= 2*FB*CC) return;
    int c = i & 3;
    int k = (i >> 2) % FB;
    int m = i / (FB*CC);
    double coef = 2.0*PI_D*50.0*0.027*sin(40.0*PI_D/180.0)/340.0;
    double sgn = (m == 0) ? -1.0 : 1.0;   // beam 0 = -40 deg, beam 1 = +40 deg
    double ph = sgn*coef*(double)k*(double)c;
    double s, c2;
    sincos(ph, &s, &c2);
    ((float2*)htab)[i] = make_float2((float)c2, (float)s);
}

// ---------- stage 1: per-(b,chunk) partial {sum4, min4, max4} over L (single pass, float4) ----------
__global__ __launch_bounds__(256) void k_stats1(const float* __restrict__ in, float* __restrict__ part){
    __shared__ float4 s4[256];
    __shared__ float4 mn4[256];
    __shared__ float4 mx4[256];
    int b = blockIdx.x / RBLK, chunk = blockIdx.x % RBLK;
    int tid = threadIdx.x;
    const float4* p = (const float4*)(in + (size_t)b*LL*CC);
    const int per = LL / RBLK;                 // 1250 float4 samples per chunk
    int start = chunk*per;
    float4 s  = make_float4(0.f,0.f,0.f,0.f);
    float4 mn = make_float4( 3.4e38f, 3.4e38f, 3.4e38f, 3.4e38f);
    float4 mx = make_float4(-3.4e38f,-3.4e38f,-3.4e38f,-3.4e38f);
    for (int i = start + tid; i < start + per; i += 256){
        float4 v = p[i];
        s.x += v.x; s.y += v.y; s.z += v.z; s.w += v.w;
        mn.x = fminf(mn.x, v.x); mn.y = fminf(mn.y, v.y); mn.z = fminf(mn.z, v.z); mn.w = fminf(mn.w, v.w);
        mx.x = fmaxf(mx.x, v.x); mx.y = fmaxf(mx.y, v.y); mx.z = fmaxf(mx.z, v.z); mx.w = fmaxf(mx.w, v.w);
    }
    s4[tid] = s; mn4[tid] = mn; mx4[tid] = mx;
    __syncthreads();
    for (int st = 128; st >= 1; st >>= 1){
        if (tid < st){
            float4 a = s4[tid], c = s4[tid+st];
            s4[tid] = make_float4(a.x+c.x, a.y+c.y, a.z+c.z, a.w+c.w);
            float4 d = mn4[tid], e = mn4[tid+st];
            mn4[tid] = make_float4(fminf(d.x,e.x), fminf(d.y,e.y), fminf(d.z,e.z), fminf(d.w,e.w));
            float4 f = mx4[tid], g = mx4[tid+st];
            mx4[tid] = make_float4(fmaxf(f.x,g.x), fmaxf(f.y,g.y), fmaxf(f.z,g.z), fmaxf(f.w,g.w));
        }
        __syncthreads();
    }
    if (tid == 0){
        float* dst = part + (size_t)(b*RBLK + chunk)*12;
        float4 a = s4[0], d = mn4[0], f = mx4[0];
        dst[0]=a.x; dst[1]=a.y; dst[2]=a.z; dst[3]=a.w;
        dst[4]=d.x; dst[5]=d.y; dst[6]=d.z; dst[7]=d.w;
        dst[8]=f.x; dst[9]=f.y; dst[10]=f.z; dst[11]=f.w;
    }
}

// ---------- stage 2: finalize mean + invmax per batch ----------
__global__ __launch_bounds__(128) void k_stats2(const float* __restrict__ part,
                                                float* __restrict__ mean, float* __restrict__ invmax){
    __shared__ float4 s4[128];
    __shared__ float4 mn4[128];
    __shared__ float4 mx4[128];
    int b = blockIdx.x, tid = threadIdx.x;
    const float* src = part + (size_t)(b*RBLK + tid)*12;
    s4[tid]  = make_float4(src[0], src[1], src[2], src[3]);
    mn4[tid] = make_float4(src[4], src[5], src[6], src[7]);
    mx4[tid] = make_float4(src[8], src[9], src[10], src[11]);
    __syncthreads();
    for (int st = 64; st >= 1; st >>= 1){
        if (tid < st){
            float4 a = s4[tid], c = s4[tid+st];
            s4[tid] = make_float4(a.x+c.x, a.y+c.y, a.z+c.z, a.w+c.w);
            float4 d = mn4[tid], e = mn4[tid+st];
            mn4[tid] = make_float4(fminf(d.x,e.x), fminf(d.y,e.y), fminf(d.z,e.z), fminf(d.w,e.w));
            float4 f = mx4[tid], g = mx4[tid+st];
            mx4[tid] = make_float4(fmaxf(f.x,g.x), fmaxf(f.y,g.y), fmaxf(f.z,g.z), fmaxf(f.w,g.w));
        }
        __syncthreads();
    }
    if (tid == 0){
        float4 sum = s4[0], mn = mn4[0], mx = mx4[0];
        float m0 = sum.x*(1.0f/LL), m1 = sum.y*(1.0f/LL), m2 = sum.z*(1.0f/LL), m3 = sum.w*(1.0f/LL);
        mean[b*4+0]=m0; mean[b*4+1]=m1; mean[b*4+2]=m2; mean[b*4+3]=m3;
        float a0 = fmaxf(mx.x - m0, m0 - mn.x);
        float a1 = fmaxf(mx.y - m1, m1 - mn.y);
        float a2 = fmaxf(mx.z - m2, m2 - mn.z);
        float a3 = fmaxf(mx.w - m3, m3 - mn.w);
        invmax[b] = 1.0f / fmaxf(fmaxf(a0, a1), fmaxf(a2, a3));
    }
}

// ---------- STFT: direct DFT, 8-frame tile per block, 4 channels packed in float4 ----------
// S layout: complex S[b][k][t][c], c fastest (float4-pair per (b,k,t))
__global__ __launch_bounds__(256) void k_stft(const float* __restrict__ in, const float* __restrict__ win,
                      const float* __restrict__ mean, const float* __restrict__ invmax,
                      float* __restrict__ S){
    __shared__ float wx[8*NFFT*CC];     // [fi][n][c] -> float4 per (fi,n); 40 KB
    __shared__ float lwin[NFFT];
    __shared__ float lmean[4];
    __shared__ float linv;
    int bx = blockIdx.x;
    int b = bx / 126, tile = bx % 126;
    int t0 = tile*8;
    int tid = threadIdx.x;
    for (int i = tid; i < NFFT; i += 256) lwin[i] = win[i];
    if (tid < 4) lmean[tid] = mean[b*4 + tid];
    if (tid == 4) linv = invmax[b];
    __syncthreads();
    const float* px = in + (size_t)b*LL*CC;
    for (int i = tid; i < 8*NFFT*CC; i += 256){
        int fi = i / (NFFT*CC);
        int r  = i % (NFFT*CC);
        int n = r >> 2, c = r & 3;
        int t = t0 + fi;
        if (t < TT){
            int p = t*HOP + n - HOP;                       // reflect-padded position
            int m2 = p < 0 ? -p : (p >= LL ? 2*LL - 2 - p : p);
            wx[i] = (px[(size_t)m2*CC + c] - lmean[c]) * linv * lwin[n];
        }
    }
    __syncthreads();
    const float4* wx4 = (const float4*)wx;
    for (int o = tid; o < 8*FB; o += 256){
        int fi = o / FB, k = o % FB;
        int t = t0 + fi;
        if (t >= TT) continue;
        float sa, ca;
        sincosf(-2.0f*(float)PI_D*(float)k/(float)NFFT, &sa, &ca);
        float2 rot = make_float2(ca, sa);
        float2 cur = make_float2(1.f, 0.f);
        float2 a0 = make_float2(0.f,0.f), a1 = a0, a2 = a0, a3 = a0;
        int base = fi*NFFT;
        for (int n = 0; n < NFFT; ++n){
            float4 w4 = wx4[base + n];                     // LDS broadcast (same addr all lanes)
            a0.x += w4.x*cur.x; a0.y += w4.x*cur.y;
            a1.x += w4.y*cur.x; a1.y += w4.y*cur.y;
            a2.x += w4.z*cur.x; a2.y += w4.z*cur.y;
            a3.x += w4.w*cur.x; a3.y += w4.w*cur.y;
            cur = cmulf(cur, rot);
        }
        size_t idx = ((size_t)(b*FB + k)*TT + t)*2;        // float4 units
        float4* S4 = (float4*)S;
        S4[idx]   = make_float4(a0.x, a0.y, a1.x, a1.y);
        S4[idx+1] = make_float4(a2.x, a2.y, a3.x, a3.y);
    }
}

// ---------- scan replaced by truncated exponential sum + Cholesky solve + beamform ----------
// S1/S2 layout: complex [b][f][t]
__global__ __launch_bounds__(256) void k_scan(const float* __restrict__ S, const float* __restrict__ htab,
                      float* __restrict__ S1, float* __restrict__ S2){
    int o = blockIdx.x*256 + threadIdx.x;
    if (o >= BB*FB*TT) return;
    int t  = o % TT;
    int bf = o / TT;               // b*FB + f
    int f  = bf % FB;
    const float4* Sp = (const float4*)S;
    size_t base4 = (size_t)bf*TT*2;
    float d0=0,d1=0,d2=0,d3=0;
    float2 r10={0,0}, r20={0,0}, r30={0,0}, r21={0,0}, r31={0,0}, r32={0,0};
    float2 X0={0,0}, X1={0,0}, X2={0,0}, X3={0,0};
    int tau0 = t - (KSPAN-1); if (tau0 < 0) tau0 = 0;
    float w = 0.95f;
    for (int tau = t; tau >= tau0; --tau){
        float4 v0 = Sp[base4 + (size_t)tau*2];
        float4 v1 = Sp[base4 + (size_t)tau*2 + 1];
        float2 x0 = make_float2(v0.x, v0.y), x1 = make_float2(v0.z, v0.w);
        float2 x2 = make_float2(v1.x, v1.y), x3 = make_float2(v1.z, v1.w);
        if (tau == t){ X0=x0; X1=x1; X2=x2; X3=x3; }
        float wt = (tau == 0) ? w*(1.0f/0.95f) : w;
        float y0x=wt*x0.x, y0y=wt*x0.y, y1x=wt*x1.x, y1y=wt*x1.y;
        float y2x=wt*x2.x, y2y=wt*x2.y, y3x=wt*x3.x, y3y=wt*x3.y;
        d0 += y0x*x0.x + y0y*x0.y;
        d1 += y1x*x1.x + y1y*x1.y;
        d2 += y2x*x2.x + y2y*x2.y;
        d3 += y3x*x3.x + y3y*x3.y;
        r10.x += y1x*x0.x + y1y*x0.y;  r10.y += y1y*x0.x - y1x*x0.y;
        r20.x += y2x*x0.x + y2y*x0.y;  r20.y += y2y*x0.x - y2x*x0.y;
        r30.x += y3x*x0.x + y3y*x0.y;  r30.y += y3y*x0.x - y3x*x0.y;
        r21.x += y2x*x1.x + y2y*x1.y;  r21.y += y2y*x1.x - y2x*x1.y;
        r31.x += y3x*x1.x + y3y*x1.y;  r31.y += y3y*x1.x - y3x*x1.y;
        r32.x += y3x*x2.x + y3y*x2.y;  r32.y += y3y*x2.x - y3x*x2.y;
        w *= 0.05f;
    }
    float tr  = d0 + d1 + d2 + d3;
    float lam = tr * 0.25f;
    float a00 = d0 + lam, a11 = d1 + lam, a22 = d2 + lam, a33 = d3 + lam;
    float l00 = sqrtf(a00);                       float i00 = 1.0f/l00;
    float2 L10 = cscale(r10, i00);
    float2 L20 = cscale(r20, i00);
    float2 L30 = cscale(r30, i00);
    float l11 = sqrtf(a11 - (L10.x*L10.x + L10.y*L10.y));                 float i11 = 1.0f/l11;
    float2 L21 = cscale(csub(r21, cmulcj(L20, L10)), i11);
    float2 L31 = cscale(csub(r31, cmulcj(L30, L10)), i11);
    float l22 = sqrtf(a22 - (L20.x*L20.x+L20.y*L20.y) - (L21.x*L21.x+L21.y*L21.y)); float i22 = 1.0f/l22;
    float2 L32 = cscale(csub(csub(r32, cmulcj(L30, L20)), cmulcj(L31, L21)), i22);
    float l33 = sqrtf(a33 - (L30.x*L30.x+L30.y*L30.y) - (L31.x*L31.x+L31.y*L31.y)
                          - (L32.x*L32.x+L32.y*L32.y));                   float i33 = 1.0f/l33;
    const float2* hp = (const float2*)htab;
    for (int m = 0; m < 2; ++m){
        float2 h0 = hp[(m*FB + f)*4 + 0];
        float2 h1 = hp[(m*FB + f)*4 + 1];
        float2 h2 = hp[(m*FB + f)*4 + 2];
        float2 h3 = hp[(m*FB + f)*4 + 3];
        float2 u0 = cscale(h0, i00);
        float2 u1 = cscale(csub(h1, cmulf(L10,u0)), i11);
        float2 u2 = cscale(csub(csub(h2, cmulf(L20,u0)), cmulf(L21,u1)), i22);
        float2 u3 = cscale(csub(csub(csub(h3, cmulf(L30,u0)), cmulf(L31,u1)), cmulf(L32,u2)), i33);
        float2 y3v = cscale(u3, i33);
        float2 y2v = cscale(csub(u2, cjmul(L32, y3v)), i22);
        float2 y1v = cscale(csub(csub(u1, cjmul(L21, y2v)), cjmul(L31, y3v)), i11);
        float2 y0v = cscale(csub(csub(csub(u0, cjmul(L10, y1v)), cjmul(L20, y2v)), cjmul(L30, y3v)), i00);
        float2 den = cjmul(h0, y0v), tmp;
        tmp = cjmul(h1, y1v); den.x += tmp.x; den.y += tmp.y;
        tmp = cjmul(h2, y2v); den.x += tmp.x; den.y += tmp.y;
        tmp = cjmul(h3, y3v); den.x += tmp.x; den.y += tmp.y;
        float2 num = cjmul(y0v, X0);
        tmp = cjmul(y1v, X1); num.x += tmp.x; num.y += tmp.y;
        tmp = cjmul(y2v, X2); num.x += tmp.x; num.y += tmp.y;
        tmp = cjmul(y3v, X3); num.x += tmp.x; num.y += tmp.y;
        float2 s = cdivf(num, make_float2(den.x, -den.y));
        float* dst = (m == 0) ? S1 : S2;
        ((float2*)dst)[(size_t)bf*TT + t] = s;
    }
}

// ---------- pack: S1/S2 complex [b][f][t] -> A bf16 [row=(beam*8+b)*1001+t][LDK] (hi | lo) ----------
__global__ __launch_bounds__(256) void k_pack(const float* __restrict__ S1, const float* __restrict__ S2,
                                              short* __restrict__ A){
    int tx = threadIdx.x;               // 0..63 (kk)
    int ty = threadIdx.y;               // 0..3  (row)
    int kk = blockIdx.x*64 + tx;        // 0..703
    int row = blockIdx.y*4 + ty;        // 0..16015
    if (row >= GM) return;
    int sec = (kk >= KSEC) ? 1 : 0;
    int kk2 = kk - (sec ? KSEC : 0);
    float v = 0.f;
    if (kk2 < 2*FB){
        int bin = kk2 >> 1;
        int t   = row % TT;
        int rb  = row / TT;
        int beam = rb >> 3, b = rb & 7;
        const float2* Sp = (const float2*)(beam ? S2 : S1);
        float2 s = Sp[(size_t)(b*FB + bin)*TT + t];
        v = (kk2 & 1) ? s.y : s.x;
    }
    A[(size_t)row*LDK + kk] = sec ? bf_lo(v) : bf_hi(v);
}

// ---------- Bt gen: Bt[n][LDK] bf16, irfft twiddles (fp64), hi | lo sections ----------
__global__ void k_bgen(short* __restrict__ Bt){
    int gid = blockIdx.x*256 + threadIdx.x;
    if (gid >= NFFT*LDK) return;
    int n = gid / LDK, kk = gid % LDK;
    int sec = (kk >= KSEC) ? 1 : 0;
    int kk2 = kk - (sec ? KSEC : 0);
    float v = 0.f;
    if (kk2 < 2*FB){
        int bin = kk2 >> 1;
        double c = ((bin == 0 || bin == 160) ? 1.0 : 2.0) / 320.0;
        double th = 2.0*PI_D*(double)bin*(double)n/320.0;
        double s, co; sincos(th, &s, &co);
        v = (float)((kk2 & 1) ? -c*s : c*co);
    }
    Bt[(size_t)n*LDK + kk] = sec ? bf_lo(v) : bf_hi(v);
}

// ---------- MFMA GEMM: frames[GM,320] = sum over 3 segments (Ahi*Bhi + Alo*Bhi + Ahi*Blo) ----------
__global__ __launch_bounds__(256) void k_gemm(const short* __restrict__ A, const short* __restrict__ Bt,
                                              float* __restrict__ C){
    __shared__ short As[64*40];     // 64 rows x 32 k, +8 pad
    __shared__ short Bs[64*40];
    int tid = threadIdx.x;
    int row0 = blockIdx.x * 64;
    int col0 = blockIdx.y * 64;
    int wave = tid >> 6, lane = tid & 63;
    int wm = wave >> 1, wn = wave & 1;
    int l15 = lane & 15, quad = lane >> 4;
    f32x4 acc00 = {0.f,0.f,0.f,0.f}, acc01 = acc00, acc10 = acc00, acc11 = acc00;
    int tr = tid >> 2;              // 0..63 tile row
    int tk = (tid & 3) * 8;         // 0,8,16,24
    int gr = row0 + tr;
    bool rok = gr < GM;
    const size_t arow = (size_t)gr*LDK;
    const size_t brow = (size_t)(col0 + tr)*LDK;
    for (int seg = 0; seg < 3; ++seg){
        int aofs = (seg == 1) ? KSEC : 0;
        int bofs = (seg == 2) ? KSEC : 0;
        for (int kt = 0; kt < KT; ++kt){
            int k0 = kt*32;
            __syncthreads();
            bf16x8 av = {};
            if (rok) av = *(const bf16x8*)&A[arow + aofs + k0 + tk];
            bf16x8 bv = *(const bf16x8*)&Bt[brow + bofs + k0 + tk];
            *(bf16x8*)&As[tr*40 + tk] = av;
            *(bf16x8*)&Bs[tr*40 + tk] = bv;
            __syncthreads();
            bf16x8 a0 = *(bf16x8*)&As[(wm*32 + l15)*40 + quad*8];
            bf16x8 a1 = *(bf16x8*)&As[(wm*32 + 16 + l15)*40 + quad*8];
            bf16x8 b0 = *(bf16x8*)&Bs[(wn*32 + l15)*40 + quad*8];
            bf16x8 b1 = *(bf16x8*)&Bs[(wn*32 + 16 + l15)*40 + quad*8];
            acc00 = __builtin_amdgcn_mfma_f32_16x16x32_bf16(a0, b0, acc00, 0, 0, 0);
            acc01 = __builtin_amdgcn_mfma_f32_16x16x32_bf16(a0, b1, acc01, 0, 0, 0);
            acc10 = __builtin_amdgcn_mfma_f32_16x16x32_bf16(a1, b0, acc10, 0, 0, 0);
            acc11 = __builtin_amdgcn_mfma_f32_16x16x32_bf16(a1, b1, acc11, 0, 0, 0);
        }
    }
    for (int r = 0; r < 4; ++r){
        int orow0 = row0 + wm*32 + quad*4 + r;
        int ocol0 = col0 + wn*32 + l15;
        if (orow0 < GM){
            C[(size_t)orow0*NFFT + ocol0]      = acc00[r];
            C[(size_t)orow0*NFFT + ocol0 + 16] = acc01[r];
        }
        if (orow0 + 16 < GM){
            C[(size_t)(orow0+16)*NFFT + ocol0]      = acc10[r];
            C[(size_t)(orow0+16)*NFFT + ocol0 + 16] = acc11[r];
        }
    }
}

// ---------- overlap-add (wsum==2 everywhere in cropped interior) ----------
__global__ void k_ola(const float* __restrict__ frames, float* __restrict__ out){
    int gid = blockIdx.x*256 + threadIdx.x;
    if (gid >= 2*BB*LL) return;
    int o  = gid % LL;
    int rb = gid / LL;                     // beam*BB + b
    int i  = o + HOP;                      // position in padded OLA buffer
    int t1 = i / HOP;                      // 1..1000
    int r  = i - t1*HOP;                   // 0..159
    const float* fb = frames + (size_t)rb*TT*NFFT;
    float v = fb[(size_t)t1*NFFT + r] + fb[(size_t)(t1-1)*NFFT + r + HOP];
    out[gid] = v * 0.5f;
}

extern "C" void kernel_launch(void* const* d_in, const int* in_sizes, int n_in,
                              void* d_out, int out_size, void* d_ws, size_t ws_size,
                              hipStream_t stream){
    const float* in  = (const float*)d_in[0];   // [B, L, C] fp32
    const float* win = (const float*)d_in[1];   // [320] fp32
    float* ws = (float*)d_ws;
    // workspace (floats): header 2624 | S1 (2,578,576) | S2 (2,578,576) | S (10,314,304)
    // aliases: part -> S1 (pre-scan); A (5,637,632 fl-equiv) + Bt (112,640) -> S (post-scan);
    //          frames (5,125,120) -> S1+S2 (post-pack). Total = 61.9 MB, same as R1/R2.
    float* mean   = ws;
    float* invmax = ws + 32;
    float* htab   = ws + 48;
    float* S1     = ws + 2624;
    size_t nS1 = (size_t)2*BB*FB*TT;            // 2,578,576 floats
    float* S2 = S1 + nS1;
    float* S  = S2 + nS1;                       // 10,314,304 floats
    float* part = S1;                           // stats partials, dead before k_scan
    short* A  = (short*)S;                      // 16016*704 bf16 = 5,637,632 float-equiv
    short* Bt = (short*)(S + 5637632);          // 320*704 bf16 = 112,640 float-equiv (16B aligned)
    float* frames = S1;                         // 16016*320 floats over dead S1+S2

    k_htab<<<dim3(6), dim3(256), 0, stream>>>(htab);
    k_stats1<<<dim3(BB*RBLK), dim3(256), 0, stream>>>(in, part);
    k_stats2<<<dim3(BB), dim3(128), 0, stream>>>(part, mean, invmax);
    k_stft<<<dim3(BB*126), dim3(256), 0, stream>>>(in, win, mean, invmax, S);
    int ntup = BB*FB*TT;
    k_scan<<<dim3((ntup + 255)/256), dim3(256), 0, stream>>>(S, htab, S1, S2);
    k_bgen<<<dim3((NFFT*LDK + 255)/256), dim3(256), 0, stream>>>(Bt);
    k_pack<<<dim3(LDK/64, (GM + 3)/4), dim3(64, 4), 0, stream>>>(S1, S2, A);
    k_gemm<<<dim3((GM + 63)/64, NFFT/64), dim3(256), 0, stream>>>(A, Bt, frames);
    k_ola<<<dim3((2*BB*LL + 255)/256), dim3(256), 0, stream>>>(frames, (float*)d_out);
}

// Round 4
// 332.197 us; speedup vs baseline: 3.8477x; 1.1128x over previous
//
#include <hip/hip_runtime.h>
#include <hip/hip_bf16.h>
#include <math.h>

#define BB 8
#define LL 160000
#define CC 4
#define NFFT 320
#define HOP 160
#define FB 161          // rfft bins
#define TT 1001         // frames
#define TP 1024         // padded frames per batch (t-slots) for STFT GEMM
#define KSPAN 16        // 0.05^16 ~ 1.5e-21: exact in fp32
#define RBLK 128        // stats blocks per batch
#define PI_D 3.14159265358979323846

#define GM 16016        // irfft GEMM M = 2*BB*TT rows (beam,b,t)
#define KSEC 352        // irfft padded K per split-section (322 used)
#define LDK 704         // irfft A/Bt leading dim = 2 sections
#define KT 11           // irfft K-tiles of 32 per section

typedef __attribute__((ext_vector_type(8))) short bf16x8;
typedef __attribute__((ext_vector_type(4))) float f32x4;

__device__ __forceinline__ float2 cmulf(float2 a, float2 b){           // a*b
    return make_float2(a.x*b.x - a.y*b.y, a.x*b.y + a.y*b.x);
}
__device__ __forceinline__ float2 cmulcj(float2 a, float2 b){          // a*conj(b)
    return make_float2(a.x*b.x + a.y*b.y, a.y*b.x - a.x*b.y);
}
__device__ __forceinline__ float2 cjmul(float2 a, float2 b){           // conj(a)*b
    return make_float2(a.x*b.x + a.y*b.y, a.x*b.y - a.y*b.x);
}
__device__ __forceinline__ float2 csub(float2 a, float2 b){ return make_float2(a.x-b.x, a.y-b.y); }
__device__ __forceinline__ float2 cscale(float2 a, float s){ return make_float2(a.x*s, a.y*s); }
__device__ __forceinline__ float2 cdivf(float2 a, float2 b){           // a/b
    float inv = 1.0f/(b.x*b.x + b.y*b.y);
    return make_float2((a.x*b.x + a.y*b.y)*inv, (a.y*b.x - a.x*b.y)*inv);
}
__device__ __forceinline__ short bf_hi(float v){
    __hip_bfloat16 h = __float2bfloat16(v);
    short s; __builtin_memcpy(&s, &h, 2); return s;
}
__device__ __forceinline__ short bf_lo(float v){
    __hip_bfloat16 h = __float2bfloat16(v);
    float r = v - __bfloat162float(h);
    __hip_bfloat16 l = __float2bfloat16(r);
    short s; __builtin_memcpy(&s, &l, 2); return s;
}

// ---------- steering table: htab[m][k][c] = exp(i*sgn_m*coef*k*c), fp64 then cast ----------
__global__ void k_htab(float* __restrict__ htab){
    int i = blockIdx.x*blockDim.x + threadIdx.x;
    if (i >= 2*FB*CC) return;
    int c = i & 3;
    int k = (i >> 2) % FB;
    int m = i / (FB*CC);
    double coef = 2.0*PI_D*50.0*0.027*sin(40.0*PI_D/180.0)/340.0;
    double sgn = (m == 0) ? -1.0 : 1.0;
    double ph = sgn*coef*(double)k*(double)c;
    double s, c2;
    sincos(ph, &s, &c2);
    ((float2*)htab)[i] = make_float2((float)c2, (float)s);
}

// ---------- stage 1: per-(b,chunk) partial {sum4, min4, max4} ----------
__global__ __launch_bounds__(256) void k_stats1(const float* __restrict__ in, float* __restrict__ part){
    __shared__ float4 s4[256];
    __shared__ float4 mn4[256];
    __shared__ float4 mx4[256];
    int b = blockIdx.x / RBLK, chunk = blockIdx.x % RBLK;
    int tid = threadIdx.x;
    const float4* p = (const float4*)(in + (size_t)b*LL*CC);
    const int per = LL / RBLK;
    int start = chunk*per;
    float4 s  = make_float4(0.f,0.f,0.f,0.f);
    float4 mn = make_float4( 3.4e38f, 3.4e38f, 3.4e38f, 3.4e38f);
    float4 mx = make_float4(-3.4e38f,-3.4e38f,-3.4e38f,-3.4e38f);
    for (int i = start + tid; i < start + per; i += 256){
        float4 v = p[i];
        s.x += v.x; s.y += v.y; s.z += v.z; s.w += v.w;
        mn.x = fminf(mn.x, v.x); mn.y = fminf(mn.y, v.y); mn.z = fminf(mn.z, v.z); mn.w = fminf(mn.w, v.w);
        mx.x = fmaxf(mx.x, v.x); mx.y = fmaxf(mx.y, v.y); mx.z = fmaxf(mx.z, v.z); mx.w = fmaxf(mx.w, v.w);
    }
    s4[tid] = s; mn4[tid] = mn; mx4[tid] = mx;
    __syncthreads();
    for (int st = 128; st >= 1; st >>= 1){
        if (tid < st){
            float4 a = s4[tid], c = s4[tid+st];
            s4[tid] = make_float4(a.x+c.x, a.y+c.y, a.z+c.z, a.w+c.w);
            float4 d = mn4[tid], e = mn4[tid+st];
            mn4[tid] = make_float4(fminf(d.x,e.x), fminf(d.y,e.y), fminf(d.z,e.z), fminf(d.w,e.w));
            float4 f = mx4[tid], g = mx4[tid+st];
            mx4[tid] = make_float4(fmaxf(f.x,g.x), fmaxf(f.y,g.y), fmaxf(f.z,g.z), fmaxf(f.w,g.w));
        }
        __syncthreads();
    }
    if (tid == 0){
        float* dst = part + (size_t)(b*RBLK + chunk)*12;
        float4 a = s4[0], d = mn4[0], f = mx4[0];
        dst[0]=a.x; dst[1]=a.y; dst[2]=a.z; dst[3]=a.w;
        dst[4]=d.x; dst[5]=d.y; dst[6]=d.z; dst[7]=d.w;
        dst[8]=f.x; dst[9]=f.y; dst[10]=f.z; dst[11]=f.w;
    }
}

// ---------- stage 2: finalize mean + invmax per batch ----------
__global__ __launch_bounds__(128) void k_stats2(const float* __restrict__ part,
                                                float* __restrict__ mean, float* __restrict__ invmax){
    __shared__ float4 s4[128];
    __shared__ float4 mn4[128];
    __shared__ float4 mx4[128];
    int b = blockIdx.x, tid = threadIdx.x;
    const float* src = part + (size_t)(b*RBLK + tid)*12;
    s4[tid]  = make_float4(src[0], src[1], src[2], src[3]);
    mn4[tid] = make_float4(src[4], src[5], src[6], src[7]);
    mx4[tid] = make_float4(src[8], src[9], src[10], src[11]);
    __syncthreads();
    for (int st = 64; st >= 1; st >>= 1){
        if (tid < st){
            float4 a = s4[tid], c = s4[tid+st];
            s4[tid] = make_float4(a.x+c.x, a.y+c.y, a.z+c.z, a.w+c.w);
            float4 d = mn4[tid], e = mn4[tid+st];
            mn4[tid] = make_float4(fminf(d.x,e.x), fminf(d.y,e.y), fminf(d.z,e.z), fminf(d.w,e.w));
            float4 f = mx4[tid], g = mx4[tid+st];
            mx4[tid] = make_float4(fmaxf(f.x,g.x), fmaxf(f.y,g.y), fmaxf(f.z,g.z), fmaxf(f.w,g.w));
        }
        __syncthreads();
    }
    if (tid == 0){
        float4 sum = s4[0], mn = mn4[0], mx = mx4[0];
        float m0 = sum.x*(1.0f/LL), m1 = sum.y*(1.0f/LL), m2 = sum.z*(1.0f/LL), m3 = sum.w*(1.0f/LL);
        mean[b*4+0]=m0; mean[b*4+1]=m1; mean[b*4+2]=m2; mean[b*4+3]=m3;
        float a0 = fmaxf(mx.x - m0, m0 - mn.x);
        float a1 = fmaxf(mx.y - m1, m1 - mn.y);
        float a2 = fmaxf(mx.z - m2, m2 - mn.z);
        float a3 = fmaxf(mx.w - m3, m3 - mn.w);
        invmax[b] = 1.0f / fmaxf(fmaxf(a0, a1), fmaxf(a2, a3));
    }
}

// ---------- STFT B-matrix: Bts[col][640] bf16, col=2k+ri, win folded in; hi | lo K-sections ----------
__global__ void k_bgen_s(const float* __restrict__ win, short* __restrict__ Bts){
    int gid = blockIdx.x*256 + threadIdx.x;
    if (gid >= 384*640) return;
    int col = gid / 640, kk = gid % 640;
    int n = (kk >= 320) ? kk - 320 : kk;
    int sec = (kk >= 320) ? 1 : 0;
    float v = 0.f;
    if (col < 2*FB){
        int k = col >> 1;
        double th = 2.0*PI_D*(double)k*(double)n/320.0;
        double s, co; sincos(th, &s, &co);
        double tw = (col & 1) ? -s : co;
        v = (float)((double)win[n]*tw);
    }
    Bts[gid] = sec ? bf_lo(v) : bf_hi(v);
}

// ---------- W = DFT(win) per col (fp64), for mean-correction in STFT epilogue ----------
__global__ void k_wb(const float* __restrict__ win, float* __restrict__ WBc){
    int col = blockIdx.x*64 + threadIdx.x;
    if (col >= 384) return;
    float v = 0.f;
    if (col < 2*FB){
        int k = col >> 1;
        double acc = 0.0;
        for (int n = 0; n < 320; ++n){
            double th = 2.0*PI_D*(double)k*(double)n/320.0;
            double s, co; sincos(th, &s, &co);
            acc += (double)win[n]*((col & 1) ? -s : co);
        }
        v = (float)acc;
    }
    WBc[col] = v;
}

// ---------- STFT as MFMA GEMM: rows=(b,t,c), cols=(k,ri); A staged raw from input ----------
// S out layout: complex S[b][k][t][c], c fastest (two float4 per (b,k,t)) — same as before
__global__ __launch_bounds__(256) void k_gstft(const float* __restrict__ in,
        const float* __restrict__ mean, const float* __restrict__ invmax,
        const short* __restrict__ Bts, const float* __restrict__ WBc,
        float* __restrict__ S){
    __shared__ short stage[4*2560];          // Ah|Al|Bh|Bl, 20.5 KB; Ct (16.9 KB) overlays after K-loop
    __shared__ float lmean[4];
    __shared__ float linv;
    short* Ah = stage;
    short* Al = stage + 2560;
    short* Bh = stage + 5120;
    short* Bl = stage + 7680;
    float* Ct = (float*)stage;               // 64 x 66 floats
    int tid = threadIdx.x;
    int row0 = blockIdx.x*64;                // over b*TP*CC rows
    int col0 = blockIdx.y*64;
    int b  = row0 >> 12;                     // TP*CC = 4096 rows per batch
    int t0 = (row0 & 4095) >> 2;
    if (tid < 4) lmean[tid] = mean[b*4 + tid];
    if (tid == 4) linv = invmax[b];
    int tr = tid >> 2, tq = tid & 3, tk = tq*8;
    int tloc = t0 + (tr >> 2);
    int c    = tr & 3;
    bool vt  = tloc < TT;
    const float* px = in + (size_t)b*LL*CC + c;
    int pbase = tloc*HOP - HOP;
    int wave = tid >> 6, lane = tid & 63;
    int wm = wave >> 1, wn = wave & 1;
    int l15 = lane & 15, quad = lane >> 4;
    f32x4 acc00 = {0.f,0.f,0.f,0.f}, acc01 = acc00, acc10 = acc00, acc11 = acc00;
    for (int kt = 0; kt < 10; ++kt){
        int k0 = kt*32;
        __syncthreads();
        bf16x8 hv = {}, lv = {};
        if (vt){
            #pragma unroll
            for (int j = 0; j < 8; ++j){
                int p = pbase + k0 + tk + j;
                int m2 = p < 0 ? -p : p;
                if (m2 >= LL) m2 = 2*LL - 2 - m2;
                float v = px[(size_t)m2*CC];
                __hip_bfloat16 h = __float2bfloat16(v);
                float r = v - __bfloat162float(h);
                __hip_bfloat16 l = __float2bfloat16(r);
                short hs, ls; __builtin_memcpy(&hs, &h, 2); __builtin_memcpy(&ls, &l, 2);
                hv[j] = hs; lv[j] = ls;
            }
        }
        *(bf16x8*)&Ah[tr*40 + tk] = hv;
        *(bf16x8*)&Al[tr*40 + tk] = lv;
        const short* bp = Bts + (size_t)(col0 + tr)*640 + k0 + tk;
        *(bf16x8*)&Bh[tr*40 + tk] = *(const bf16x8*)bp;
        *(bf16x8*)&Bl[tr*40 + tk] = *(const bf16x8*)(bp + 320);
        __syncthreads();
        bf16x8 a0h = *(bf16x8*)&Ah[(wm*32 + l15)*40 + quad*8];
        bf16x8 a1h = *(bf16x8*)&Ah[(wm*32 + 16 + l15)*40 + quad*8];
        bf16x8 a0l = *(bf16x8*)&Al[(wm*32 + l15)*40 + quad*8];
        bf16x8 a1l = *(bf16x8*)&Al[(wm*32 + 16 + l15)*40 + quad*8];
        bf16x8 b0h = *(bf16x8*)&Bh[(wn*32 + l15)*40 + quad*8];
        bf16x8 b1h = *(bf16x8*)&Bh[(wn*32 + 16 + l15)*40 + quad*8];
        bf16x8 b0l = *(bf16x8*)&Bl[(wn*32 + l15)*40 + quad*8];
        bf16x8 b1l = *(bf16x8*)&Bl[(wn*32 + 16 + l15)*40 + quad*8];
        acc00 = __builtin_amdgcn_mfma_f32_16x16x32_bf16(a0h, b0h, acc00, 0, 0, 0);
        acc01 = __builtin_amdgcn_mfma_f32_16x16x32_bf16(a0h, b1h, acc01, 0, 0, 0);
        acc10 = __builtin_amdgcn_mfma_f32_16x16x32_bf16(a1h, b0h, acc10, 0, 0, 0);
        acc11 = __builtin_amdgcn_mfma_f32_16x16x32_bf16(a1h, b1h, acc11, 0, 0, 0);
        acc00 = __builtin_amdgcn_mfma_f32_16x16x32_bf16(a0l, b0h, acc00, 0, 0, 0);
        acc01 = __builtin_amdgcn_mfma_f32_16x16x32_bf16(a0l, b1h, acc01, 0, 0, 0);
        acc10 = __builtin_amdgcn_mfma_f32_16x16x32_bf16(a1l, b0h, acc10, 0, 0, 0);
        acc11 = __builtin_amdgcn_mfma_f32_16x16x32_bf16(a1l, b1h, acc11, 0, 0, 0);
        acc00 = __builtin_amdgcn_mfma_f32_16x16x32_bf16(a0h, b0l, acc00, 0, 0, 0);
        acc01 = __builtin_amdgcn_mfma_f32_16x16x32_bf16(a0h, b1l, acc01, 0, 0, 0);
        acc10 = __builtin_amdgcn_mfma_f32_16x16x32_bf16(a1h, b0l, acc10, 0, 0, 0);
        acc11 = __builtin_amdgcn_mfma_f32_16x16x32_bf16(a1h, b1l, acc11, 0, 0, 0);
    }
    // epilogue: mean-correction + scale, through LDS transpose, out in S layout
    int c0l = col0 + wn*32 + l15;
    int c1l = c0l + 16;
    float wb0 = (c0l < 2*FB) ? WBc[c0l] : 0.f;
    float wb1 = (c1l < 2*FB) ? WBc[c1l] : 0.f;
    __syncthreads();                       // staging reads done; Ct overlays
    #pragma unroll
    for (int r = 0; r < 4; ++r){
        int rl = wm*32 + quad*4 + r;       // channel = r (rl & 3 == r)
        float mc = lmean[r];
        Ct[rl*66 + wn*32 + l15]        = (acc00[r] - mc*wb0)*linv;
        Ct[rl*66 + wn*32 + l15 + 16]   = (acc01[r] - mc*wb1)*linv;
        Ct[(rl+16)*66 + wn*32 + l15]      = (acc10[r] - mc*wb0)*linv;
        Ct[(rl+16)*66 + wn*32 + l15 + 16] = (acc11[r] - mc*wb1)*linv;
    }
    __syncthreads();
    int tl = tid & 15, h = (tid >> 4) & 1, kq = tid >> 5;
    int t = t0 + tl;
    if (t < TT){
        float4* S4 = (float4*)S;
        for (int kk = kq; kk < 32; kk += 8){
            int kg = (col0 >> 1) + kk;
            if (kg < FB){
                float2 e0 = *(float2*)&Ct[(tl*4 + 2*h)*66 + 2*kk];
                float2 e1 = *(float2*)&Ct[(tl*4 + 2*h + 1)*66 + 2*kk];
                S4[((size_t)(b*FB + kg)*TT + t)*2 + h] = make_float4(e0.x, e0.y, e1.x, e1.y);
            }
        }
    }
}

// ---------- scan replaced by truncated exponential sum + Cholesky solve + beamform ----------
// S1/S2 layout: complex [b][f][t]
__global__ __launch_bounds__(256) void k_scan(const float* __restrict__ S, const float* __restrict__ htab,
                      float* __restrict__ S1, float* __restrict__ S2){
    int o = blockIdx.x*256 + threadIdx.x;
    if (o >= BB*FB*TT) return;
    int t  = o % TT;
    int bf = o / TT;               // b*FB + f
    int f  = bf % FB;
    const float4* Sp = (const float4*)S;
    size_t base4 = (size_t)bf*TT*2;
    float d0=0,d1=0,d2=0,d3=0;
    float2 r10={0,0}, r20={0,0}, r30={0,0}, r21={0,0}, r31={0,0}, r32={0,0};
    float2 X0={0,0}, X1={0,0}, X2={0,0}, X3={0,0};
    int tau0 = t - (KSPAN-1); if (tau0 < 0) tau0 = 0;
    float w = 0.95f;
    for (int tau = t; tau >= tau0; --tau){
        float4 v0 = Sp[base4 + (size_t)tau*2];
        float4 v1 = Sp[base4 + (size_t)tau*2 + 1];
        float2 x0 = make_float2(v0.x, v0.y), x1 = make_float2(v0.z, v0.w);
        float2 x2 = make_float2(v1.x, v1.y), x3 = make_float2(v1.z, v1.w);
        if (tau == t){ X0=x0; X1=x1; X2=x2; X3=x3; }
        float wt = (tau == 0) ? w*(1.0f/0.95f) : w;
        float y0x=wt*x0.x, y0y=wt*x0.y, y1x=wt*x1.x, y1y=wt*x1.y;
        float y2x=wt*x2.x, y2y=wt*x2.y, y3x=wt*x3.x, y3y=wt*x3.y;
        d0 += y0x*x0.x + y0y*x0.y;
        d1 += y1x*x1.x + y1y*x1.y;
        d2 += y2x*x2.x + y2y*x2.y;
        d3 += y3x*x3.x + y3y*x3.y;
        r10.x += y1x*x0.x + y1y*x0.y;  r10.y += y1y*x0.x - y1x*x0.y;
        r20.x += y2x*x0.x + y2y*x0.y;  r20.y += y2y*x0.x - y2x*x0.y;
        r30.x += y3x*x0.x + y3y*x0.y;  r30.y += y3y*x0.x - y3x*x0.y;
        r21.x += y2x*x1.x + y2y*x1.y;  r21.y += y2y*x1.x - y2x*x1.y;
        r31.x += y3x*x1.x + y3y*x1.y;  r31.y += y3y*x1.x - y3x*x1.y;
        r32.x += y3x*x2.x + y3y*x2.y;  r32.y += y3y*x2.x - y3x*x2.y;
        w *= 0.05f;
    }
    float tr  = d0 + d1 + d2 + d3;
    float lam = tr * 0.25f;
    float a00 = d0 + lam, a11 = d1 + lam, a22 = d2 + lam, a33 = d3 + lam;
    float l00 = sqrtf(a00);                       float i00 = 1.0f/l00;
    float2 L10 = cscale(r10, i00);
    float2 L20 = cscale(r20, i00);
    float2 L30 = cscale(r30, i00);
    float l11 = sqrtf(a11 - (L10.x*L10.x + L10.y*L10.y));                 float i11 = 1.0f/l11;
    float2 L21 = cscale(csub(r21, cmulcj(L20, L10)), i11);
    float2 L31 = cscale(csub(r31, cmulcj(L30, L10)), i11);
    float l22 = sqrtf(a22 - (L20.x*L20.x+L20.y*L20.y) - (L21.x*L21.x+L21.y*L21.y)); float i22 = 1.0f/l22;
    float2 L32 = cscale(csub(csub(r32, cmulcj(L30, L20)), cmulcj(L31, L21)), i22);
    float l33 = sqrtf(a33 - (L30.x*L30.x+L30.y*L30.y) - (L31.x*L31.x+L31.y*L31.y)
                          - (L32.x*L32.x+L32.y*L32.y));                   float i33 = 1.0f/l33;
    const float2* hp = (const float2*)htab;
    for (int m = 0; m < 2; ++m){
        float2 h0 = hp[(m*FB + f)*4 + 0];
        float2 h1 = hp[(m*FB + f)*4 + 1];
        float2 h2 = hp[(m*FB + f)*4 + 2];
        float2 h3 = hp[(m*FB + f)*4 + 3];
        float2 u0 = cscale(h0, i00);
        float2 u1 = cscale(csub(h1, cmulf(L10,u0)), i11);
        float2 u2 = cscale(csub(csub(h2, cmulf(L20,u0)), cmulf(L21,u1)), i22);
        float2 u3 = cscale(csub(csub(csub(h3, cmulf(L30,u0)), cmulf(L31,u1)), cmulf(L32,u2)), i33);
        float2 y3v = cscale(u3, i33);
        float2 y2v = cscale(csub(u2, cjmul(L32, y3v)), i22);
        float2 y1v = cscale(csub(csub(u1, cjmul(L21, y2v)), cjmul(L31, y3v)), i11);
        float2 y0v = cscale(csub(csub(csub(u0, cjmul(L10, y1v)), cjmul(L20, y2v)), cjmul(L30, y3v)), i00);
        float2 den = cjmul(h0, y0v), tmp;
        tmp = cjmul(h1, y1v); den.x += tmp.x; den.y += tmp.y;
        tmp = cjmul(h2, y2v); den.x += tmp.x; den.y += tmp.y;
        tmp = cjmul(h3, y3v); den.x += tmp.x; den.y += tmp.y;
        float2 num = cjmul(y0v, X0);
        tmp = cjmul(y1v, X1); num.x += tmp.x; num.y += tmp.y;
        tmp = cjmul(y2v, X2); num.x += tmp.x; num.y += tmp.y;
        tmp = cjmul(y3v, X3); num.x += tmp.x; num.y += tmp.y;
        float2 s = cdivf(num, make_float2(den.x, -den.y));
        float* dst = (m == 0) ? S1 : S2;
        ((float2*)dst)[(size_t)bf*TT + t] = s;
    }
}

// ---------- pack: S1/S2 complex [b][f][t] -> A bf16 [row=(beam*8+b)*1001+t][LDK] (hi | lo) ----------
__global__ __launch_bounds__(256) void k_pack(const float* __restrict__ S1, const float* __restrict__ S2,
                                              short* __restrict__ A){
    int tx = threadIdx.x;               // 0..63 (kk)
    int ty = threadIdx.y;               // 0..3  (row)
    int kk = blockIdx.x*64 + tx;        // 0..703
    int row = blockIdx.y*4 + ty;        // 0..16015
    if (row >= GM) return;
    int sec = (kk >= KSEC) ? 1 : 0;
    int kk2 = kk - (sec ? KSEC : 0);
    float v = 0.f;
    if (kk2 < 2*FB){
        int bin = kk2 >> 1;
        int t   = row % TT;
        int rb  = row / TT;
        int beam = rb >> 3, b = rb & 7;
        const float2* Sp = (const float2*)(beam ? S2 : S1);
        float2 s = Sp[(size_t)(b*FB + bin)*TT + t];
        v = (kk2 & 1) ? s.y : s.x;
    }
    A[(size_t)row*LDK + kk] = sec ? bf_lo(v) : bf_hi(v);
}

// ---------- Bt gen: Bt[n][LDK] bf16, irfft twiddles (fp64), hi | lo sections ----------
__global__ void k_bgen(short* __restrict__ Bt){
    int gid = blockIdx.x*256 + threadIdx.x;
    if (gid >= NFFT*LDK) return;
    int n = gid / LDK, kk = gid % LDK;
    int sec = (kk >= KSEC) ? 1 : 0;
    int kk2 = kk - (sec ? KSEC : 0);
    float v = 0.f;
    if (kk2 < 2*FB){
        int bin = kk2 >> 1;
        double c = ((bin == 0 || bin == 160) ? 1.0 : 2.0) / 320.0;
        double th = 2.0*PI_D*(double)bin*(double)n/320.0;
        double s, co; sincos(th, &s, &co);
        v = (float)((kk2 & 1) ? -c*s : c*co);
    }
    Bt[(size_t)n*LDK + kk] = sec ? bf_lo(v) : bf_hi(v);
}

// ---------- irfft MFMA GEMM: frames[GM,320] = 3-segment bf16 split product ----------
__global__ __launch_bounds__(256) void k_gemm(const short* __restrict__ A, const short* __restrict__ Bt,
                                              float* __restrict__ C){
    __shared__ short As[64*40];
    __shared__ short Bs[64*40];
    int tid = threadIdx.x;
    int row0 = blockIdx.x * 64;
    int col0 = blockIdx.y * 64;
    int wave = tid >> 6, lane = tid & 63;
    int wm = wave >> 1, wn = wave & 1;
    int l15 = lane & 15, quad = lane >> 4;
    f32x4 acc00 = {0.f,0.f,0.f,0.f}, acc01 = acc00, acc10 = acc00, acc11 = acc00;
    int tr = tid >> 2;
    int tk = (tid & 3) * 8;
    int gr = row0 + tr;
    bool rok = gr < GM;
    const size_t arow = (size_t)gr*LDK;
    const size_t brow = (size_t)(col0 + tr)*LDK;
    for (int seg = 0; seg < 3; ++seg){
        int aofs = (seg == 1) ? KSEC : 0;
        int bofs = (seg == 2) ? KSEC : 0;
        for (int kt = 0; kt < KT; ++kt){
            int k0 = kt*32;
            __syncthreads();
            bf16x8 av = {};
            if (rok) av = *(const bf16x8*)&A[arow + aofs + k0 + tk];
            bf16x8 bv = *(const bf16x8*)&Bt[brow + bofs + k0 + tk];
            *(bf16x8*)&As[tr*40 + tk] = av;
            *(bf16x8*)&Bs[tr*40 + tk] = bv;
            __syncthreads();
            bf16x8 a0 = *(bf16x8*)&As[(wm*32 + l15)*40 + quad*8];
            bf16x8 a1 = *(bf16x8*)&As[(wm*32 + 16 + l15)*40 + quad*8];
            bf16x8 b0 = *(bf16x8*)&Bs[(wn*32 + l15)*40 + quad*8];
            bf16x8 b1 = *(bf16x8*)&Bs[(wn*32 + 16 + l15)*40 + quad*8];
            acc00 = __builtin_amdgcn_mfma_f32_16x16x32_bf16(a0, b0, acc00, 0, 0, 0);
            acc01 = __builtin_amdgcn_mfma_f32_16x16x32_bf16(a0, b1, acc01, 0, 0, 0);
            acc10 = __builtin_amdgcn_mfma_f32_16x16x32_bf16(a1, b0, acc10, 0, 0, 0);
            acc11 = __builtin_amdgcn_mfma_f32_16x16x32_bf16(a1, b1, acc11, 0, 0, 0);
        }
    }
    for (int r = 0; r < 4; ++r){
        int orow0 = row0 + wm*32 + quad*4 + r;
        int ocol0 = col0 + wn*32 + l15;
        if (orow0 < GM){
            C[(size_t)orow0*NFFT + ocol0]      = acc00[r];
            C[(size_t)orow0*NFFT + ocol0 + 16] = acc01[r];
        }
        if (orow0 + 16 < GM){
            C[(size_t)(orow0+16)*NFFT + ocol0]      = acc10[r];
            C[(size_t)(orow0+16)*NFFT + ocol0 + 16] = acc11[r];
        }
    }
}

// ---------- overlap-add (wsum==2 everywhere in cropped interior) ----------
__global__ void k_ola(const float* __restrict__ frames, float* __restrict__ out){
    int gid = blockIdx.x*256 + threadIdx.x;
    if (gid >= 2*BB*LL) return;
    int o  = gid % LL;
    int rb = gid / LL;                     // beam*BB + b
    int i  = o + HOP;
    int t1 = i / HOP;
    int r  = i - t1*HOP;
    const float* fb = frames + (size_t)rb*TT*NFFT;
    float v = fb[(size_t)t1*NFFT + r] + fb[(size_t)(t1-1)*NFFT + r + HOP];
    out[gid] = v * 0.5f;
}

extern "C" void kernel_launch(void* const* d_in, const int* in_sizes, int n_in,
                              void* d_out, int out_size, void* d_ws, size_t ws_size,
                              hipStream_t stream){
    const float* in  = (const float*)d_in[0];   // [B, L, C] fp32
    const float* win = (const float*)d_in[1];   // [320] fp32
    float* ws = (float*)d_ws;
    // ws (floats): mean 32 | invmax 8 | htab 2576 | WBc 384 (+pad) -> header 3072
    //              | S1 (2,578,576) | S2 (2,578,576) | S (10,314,304)   total ~62 MB
    // aliases: part -> S1[0:12288]; Bts -> shorts at S1+16384 (dead before k_scan);
    //          A_ir + Bt_ir -> S (post-scan); frames -> S1/S2 (post-pack)
    float* mean   = ws;
    float* invmax = ws + 32;
    float* htab   = ws + 48;
    float* WBc    = ws + 2624;
    float* S1     = ws + 3072;
    size_t nS1 = (size_t)2*BB*FB*TT;            // 2,578,576 floats
    float* S2 = S1 + nS1;
    float* S  = S2 + nS1;                       // 10,314,304 floats
    float* part = S1;
    short* Bts  = (short*)(S1 + 16384);         // 384*640 shorts
    short* A  = (short*)S;                      // irfft A: 16016*704 bf16
    short* Bt = (short*)(S + 5637632);          // irfft Bt: 320*704 bf16
    float* frames = S1;                         // 16016*320 floats over dead S1+S2

    k_htab<<<dim3(6), dim3(256), 0, stream>>>(htab);
    k_stats1<<<dim3(BB*RBLK), dim3(256), 0, stream>>>(in, part);
    k_stats2<<<dim3(BB), dim3(128), 0, stream>>>(part, mean, invmax);
    k_bgen_s<<<dim3((384*640 + 255)/256), dim3(256), 0, stream>>>(win, Bts);
    k_wb<<<dim3(6), dim3(64), 0, stream>>>(win, WBc);
    k_gstft<<<dim3(BB*TP*CC/64, 6), dim3(256), 0, stream>>>(in, mean, invmax, Bts, WBc, S);
    int ntup = BB*FB*TT;
    k_scan<<<dim3((ntup + 255)/256), dim3(256), 0, stream>>>(S, htab, S1, S2);
    k_bgen<<<dim3((NFFT*LDK + 255)/256), dim3(256), 0, stream>>>(Bt);
    k_pack<<<dim3(LDK/64, (GM + 3)/4), dim3(64, 4), 0, stream>>>(S1, S2, A);
    k_gemm<<<dim3((GM + 63)/64, NFFT/64), dim3(256), 0, stream>>>(A, Bt, frames);
    k_ola<<<dim3((2*BB*LL + 255)/256), dim3(256), 0, stream>>>(frames, (float*)d_out);
}

// Round 5
// 252.006 us; speedup vs baseline: 5.0720x; 1.3182x over previous
//
#include <hip/hip_runtime.h>
#include <hip/hip_bf16.h>
#include <math.h>

#define BB 8
#define LL 160000
#define CC 4
#define NFFT 320
#define HOP 160
#define FB 161          // rfft bins
#define TT 1001         // frames
#define TP 1024         // padded frames per batch (t-slots) for STFT GEMM
#define KSPAN 16        // 0.05^16 ~ 1.5e-21: exact in fp32
#define RBLK 128        // stats blocks per batch
#define PI_D 3.14159265358979323846

#define GM 16016        // irfft GEMM M = 2*BB*TT rows (beam,b,t)
#define KSEC 352        // irfft padded K per split-section (322 used)
#define LDK 704         // irfft A/Bt leading dim = 2 sections
#define KT 11           // irfft K-tiles of 32 per section

typedef __attribute__((ext_vector_type(8))) short bf16x8;
typedef __attribute__((ext_vector_type(4))) float f32x4;

__device__ __forceinline__ float2 cmulf(float2 a, float2 b){           // a*b
    return make_float2(a.x*b.x - a.y*b.y, a.x*b.y + a.y*b.x);
}
__device__ __forceinline__ float2 cmulcj(float2 a, float2 b){          // a*conj(b)
    return make_float2(a.x*b.x + a.y*b.y, a.y*b.x - a.x*b.y);
}
__device__ __forceinline__ float2 cjmul(float2 a, float2 b){           // conj(a)*b
    return make_float2(a.x*b.x + a.y*b.y, a.x*b.y - a.y*b.x);
}
__device__ __forceinline__ float2 csub(float2 a, float2 b){ return make_float2(a.x-b.x, a.y-b.y); }
__device__ __forceinline__ float2 cscale(float2 a, float s){ return make_float2(a.x*s, a.y*s); }
__device__ __forceinline__ float2 cdivf(float2 a, float2 b){           // a/b
    float inv = 1.0f/(b.x*b.x + b.y*b.y);
    return make_float2((a.x*b.x + a.y*b.y)*inv, (a.y*b.x - a.x*b.y)*inv);
}
__device__ __forceinline__ short bf_hi(float v){
    __hip_bfloat16 h = __float2bfloat16(v);
    short s; __builtin_memcpy(&s, &h, 2); return s;
}
__device__ __forceinline__ short bf_lo(float v){
    __hip_bfloat16 h = __float2bfloat16(v);
    float r = v - __bfloat162float(h);
    __hip_bfloat16 l = __float2bfloat16(r);
    short s; __builtin_memcpy(&s, &l, 2); return s;
}

// ---------- steering table: htab[m][k][c] = exp(i*sgn_m*coef*k*c), fp64 then cast ----------
__global__ void k_htab(float* __restrict__ htab){
    int i = blockIdx.x*blockDim.x + threadIdx.x;
    if (i >= 2*FB*CC) return;
    int c = i & 3;
    int k = (i >> 2) % FB;
    int m = i / (FB*CC);
    double coef = 2.0*PI_D*50.0*0.027*sin(40.0*PI_D/180.0)/340.0;
    double sgn = (m == 0) ? -1.0 : 1.0;
    double ph = sgn*coef*(double)k*(double)c;
    double s, c2;
    sincos(ph, &s, &c2);
    ((float2*)htab)[i] = make_float2((float)c2, (float)s);
}

// ---------- stage 1: per-(b,chunk) partial {sum4, min4, max4} ----------
__global__ __launch_bounds__(256) void k_stats1(const float* __restrict__ in, float* __restrict__ part){
    __shared__ float4 s4[256];
    __shared__ float4 mn4[256];
    __shared__ float4 mx4[256];
    int b = blockIdx.x / RBLK, chunk = blockIdx.x % RBLK;
    int tid = threadIdx.x;
    const float4* p = (const float4*)(in + (size_t)b*LL*CC);
    const int per = LL / RBLK;
    int start = chunk*per;
    float4 s  = make_float4(0.f,0.f,0.f,0.f);
    float4 mn = make_float4( 3.4e38f, 3.4e38f, 3.4e38f, 3.4e38f);
    float4 mx = make_float4(-3.4e38f,-3.4e38f,-3.4e38f,-3.4e38f);
    for (int i = start + tid; i < start + per; i += 256){
        float4 v = p[i];
        s.x += v.x; s.y += v.y; s.z += v.z; s.w += v.w;
        mn.x = fminf(mn.x, v.x); mn.y = fminf(mn.y, v.y); mn.z = fminf(mn.z, v.z); mn.w = fminf(mn.w, v.w);
        mx.x = fmaxf(mx.x, v.x); mx.y = fmaxf(mx.y, v.y); mx.z = fmaxf(mx.z, v.z); mx.w = fmaxf(mx.w, v.w);
    }
    s4[tid] = s; mn4[tid] = mn; mx4[tid] = mx;
    __syncthreads();
    for (int st = 128; st >= 1; st >>= 1){
        if (tid < st){
            float4 a = s4[tid], c = s4[tid+st];
            s4[tid] = make_float4(a.x+c.x, a.y+c.y, a.z+c.z, a.w+c.w);
            float4 d = mn4[tid], e = mn4[tid+st];
            mn4[tid] = make_float4(fminf(d.x,e.x), fminf(d.y,e.y), fminf(d.z,e.z), fminf(d.w,e.w));
            float4 f = mx4[tid], g = mx4[tid+st];
            mx4[tid] = make_float4(fmaxf(f.x,g.x), fmaxf(f.y,g.y), fmaxf(f.z,g.z), fmaxf(f.w,g.w));
        }
        __syncthreads();
    }
    if (tid == 0){
        float* dst = part + (size_t)(b*RBLK + chunk)*12;
        float4 a = s4[0], d = mn4[0], f = mx4[0];
        dst[0]=a.x; dst[1]=a.y; dst[2]=a.z; dst[3]=a.w;
        dst[4]=d.x; dst[5]=d.y; dst[6]=d.z; dst[7]=d.w;
        dst[8]=f.x; dst[9]=f.y; dst[10]=f.z; dst[11]=f.w;
    }
}

// ---------- stage 2: finalize mean + invmax per batch ----------
__global__ __launch_bounds__(128) void k_stats2(const float* __restrict__ part,
                                                float* __restrict__ mean, float* __restrict__ invmax){
    __shared__ float4 s4[128];
    __shared__ float4 mn4[128];
    __shared__ float4 mx4[128];
    int b = blockIdx.x, tid = threadIdx.x;
    const float* src = part + (size_t)(b*RBLK + tid)*12;
    s4[tid]  = make_float4(src[0], src[1], src[2], src[3]);
    mn4[tid] = make_float4(src[4], src[5], src[6], src[7]);
    mx4[tid] = make_float4(src[8], src[9], src[10], src[11]);
    __syncthreads();
    for (int st = 64; st >= 1; st >>= 1){
        if (tid < st){
            float4 a = s4[tid], c = s4[tid+st];
            s4[tid] = make_float4(a.x+c.x, a.y+c.y, a.z+c.z, a.w+c.w);
            float4 d = mn4[tid], e = mn4[tid+st];
            mn4[tid] = make_float4(fminf(d.x,e.x), fminf(d.y,e.y), fminf(d.z,e.z), fminf(d.w,e.w));
            float4 f = mx4[tid], g = mx4[tid+st];
            mx4[tid] = make_float4(fmaxf(f.x,g.x), fmaxf(f.y,g.y), fmaxf(f.z,g.z), fmaxf(f.w,g.w));
        }
        __syncthreads();
    }
    if (tid == 0){
        float4 sum = s4[0], mn = mn4[0], mx = mx4[0];
        float m0 = sum.x*(1.0f/LL), m1 = sum.y*(1.0f/LL), m2 = sum.z*(1.0f/LL), m3 = sum.w*(1.0f/LL);
        mean[b*4+0]=m0; mean[b*4+1]=m1; mean[b*4+2]=m2; mean[b*4+3]=m3;
        float a0 = fmaxf(mx.x - m0, m0 - mn.x);
        float a1 = fmaxf(mx.y - m1, m1 - mn.y);
        float a2 = fmaxf(mx.z - m2, m2 - mn.z);
        float a3 = fmaxf(mx.w - m3, m3 - mn.w);
        invmax[b] = 1.0f / fmaxf(fmaxf(a0, a1), fmaxf(a2, a3));
    }
}

// ---------- STFT B-matrix: Bts[col][640] bf16, col=2k+ri, win folded in; hi | lo K-sections ----------
__global__ void k_bgen_s(const float* __restrict__ win, short* __restrict__ Bts){
    int gid = blockIdx.x*256 + threadIdx.x;
    if (gid >= 384*640) return;
    int col = gid / 640, kk = gid % 640;
    int n = (kk >= 320) ? kk - 320 : kk;
    int sec = (kk >= 320) ? 1 : 0;
    float v = 0.f;
    if (col < 2*FB){
        int k = col >> 1;
        double th = 2.0*PI_D*(double)k*(double)n/320.0;
        double s, co; sincos(th, &s, &co);
        double tw = (col & 1) ? -s : co;
        v = (float)((double)win[n]*tw);
    }
    Bts[gid] = sec ? bf_lo(v) : bf_hi(v);
}

// ---------- STFT as MFMA GEMM: rows=(b,t,c), cols=(k,ri); A staged normalized from input ----------
// S out layout: complex S[b][k][t][c], c fastest (two float4 per (b,k,t))
__global__ __launch_bounds__(256) void k_gstft(const float* __restrict__ in,
        const float* __restrict__ mean, const float* __restrict__ invmax,
        const short* __restrict__ Bts, float* __restrict__ S){
    __shared__ short stage[4*2560];          // Ah|Al|Bh|Bl, 20.5 KB; Ct (16.9 KB) overlays after K-loop
    __shared__ float lmean[4];
    __shared__ float linv;
    short* Ah = stage;
    short* Al = stage + 2560;
    short* Bh = stage + 5120;
    short* Bl = stage + 7680;
    float* Ct = (float*)stage;               // 64 x 66 floats
    int tid = threadIdx.x;
    int row0 = blockIdx.x*64;                // over b*TP*CC rows
    int col0 = blockIdx.y*64;
    int b  = row0 >> 12;                     // TP*CC = 4096 rows per batch
    int t0 = (row0 & 4095) >> 2;
    if (tid < 4) lmean[tid] = mean[b*4 + tid];
    if (tid == 4) linv = invmax[b];
    int tr = tid >> 2, tq = tid & 3, tk = tq*8;
    int tloc = t0 + (tr >> 2);
    int c    = tr & 3;
    bool vt  = tloc < TT;
    const float* px = in + (size_t)b*LL*CC + c;
    int pbase = tloc*HOP - HOP;
    int wave = tid >> 6, lane = tid & 63;
    int wm = wave >> 1, wn = wave & 1;
    int l15 = lane & 15, quad = lane >> 4;
    f32x4 acc00 = {0.f,0.f,0.f,0.f}, acc01 = acc00, acc10 = acc00, acc11 = acc00;
    for (int kt = 0; kt < 10; ++kt){
        int k0 = kt*32;
        __syncthreads();                     // also makes lmean/linv visible at kt=0
        bf16x8 hv = {}, lv = {};
        if (vt){
            float mc = lmean[c], iv = linv;
            #pragma unroll
            for (int j = 0; j < 8; ++j){
                int p = pbase + k0 + tk + j;
                int m2 = p < 0 ? -p : p;
                if (m2 >= LL) m2 = 2*LL - 2 - m2;
                float v = (px[(size_t)m2*CC] - mc) * iv;
                __hip_bfloat16 h = __float2bfloat16(v);
                float r = v - __bfloat162float(h);
                __hip_bfloat16 l = __float2bfloat16(r);
                short hs, ls; __builtin_memcpy(&hs, &h, 2); __builtin_memcpy(&ls, &l, 2);
                hv[j] = hs; lv[j] = ls;
            }
        }
        *(bf16x8*)&Ah[tr*40 + tk] = hv;
        *(bf16x8*)&Al[tr*40 + tk] = lv;
        const short* bp = Bts + (size_t)(col0 + tr)*640 + k0 + tk;
        *(bf16x8*)&Bh[tr*40 + tk] = *(const bf16x8*)bp;
        *(bf16x8*)&Bl[tr*40 + tk] = *(const bf16x8*)(bp + 320);
        __syncthreads();
        bf16x8 a0h = *(bf16x8*)&Ah[(wm*32 + l15)*40 + quad*8];
        bf16x8 a1h = *(bf16x8*)&Ah[(wm*32 + 16 + l15)*40 + quad*8];
        bf16x8 a0l = *(bf16x8*)&Al[(wm*32 + l15)*40 + quad*8];
        bf16x8 a1l = *(bf16x8*)&Al[(wm*32 + 16 + l15)*40 + quad*8];
        bf16x8 b0h = *(bf16x8*)&Bh[(wn*32 + l15)*40 + quad*8];
        bf16x8 b1h = *(bf16x8*)&Bh[(wn*32 + 16 + l15)*40 + quad*8];
        bf16x8 b0l = *(bf16x8*)&Bl[(wn*32 + l15)*40 + quad*8];
        bf16x8 b1l = *(bf16x8*)&Bl[(wn*32 + 16 + l15)*40 + quad*8];
        acc00 = __builtin_amdgcn_mfma_f32_16x16x32_bf16(a0h, b0h, acc00, 0, 0, 0);
        acc01 = __builtin_amdgcn_mfma_f32_16x16x32_bf16(a0h, b1h, acc01, 0, 0, 0);
        acc10 = __builtin_amdgcn_mfma_f32_16x16x32_bf16(a1h, b0h, acc10, 0, 0, 0);
        acc11 = __builtin_amdgcn_mfma_f32_16x16x32_bf16(a1h, b1h, acc11, 0, 0, 0);
        acc00 = __builtin_amdgcn_mfma_f32_16x16x32_bf16(a0l, b0h, acc00, 0, 0, 0);
        acc01 = __builtin_amdgcn_mfma_f32_16x16x32_bf16(a0l, b1h, acc01, 0, 0, 0);
        acc10 = __builtin_amdgcn_mfma_f32_16x16x32_bf16(a1l, b0h, acc10, 0, 0, 0);
        acc11 = __builtin_amdgcn_mfma_f32_16x16x32_bf16(a1l, b1h, acc11, 0, 0, 0);
        acc00 = __builtin_amdgcn_mfma_f32_16x16x32_bf16(a0h, b0l, acc00, 0, 0, 0);
        acc01 = __builtin_amdgcn_mfma_f32_16x16x32_bf16(a0h, b1l, acc01, 0, 0, 0);
        acc10 = __builtin_amdgcn_mfma_f32_16x16x32_bf16(a1h, b0l, acc10, 0, 0, 0);
        acc11 = __builtin_amdgcn_mfma_f32_16x16x32_bf16(a1h, b1l, acc11, 0, 0, 0);
    }
    // epilogue: LDS transpose, out in S layout
    __syncthreads();                       // staging reads done; Ct overlays
    #pragma unroll
    for (int r = 0; r < 4; ++r){
        int rl = wm*32 + quad*4 + r;       // channel = r (rl & 3 == r)
        Ct[rl*66 + wn*32 + l15]           = acc00[r];
        Ct[rl*66 + wn*32 + l15 + 16]      = acc01[r];
        Ct[(rl+16)*66 + wn*32 + l15]      = acc10[r];
        Ct[(rl+16)*66 + wn*32 + l15 + 16] = acc11[r];
    }
    __syncthreads();
    int tl = tid & 15, h = (tid >> 4) & 1, kq = tid >> 5;
    int t = t0 + tl;
    if (t < TT){
        float4* S4 = (float4*)S;
        for (int kk = kq; kk < 32; kk += 8){
            int kg = (col0 >> 1) + kk;
            if (kg < FB){
                float2 e0 = *(float2*)&Ct[(tl*4 + 2*h)*66 + 2*kk];
                float2 e1 = *(float2*)&Ct[(tl*4 + 2*h + 1)*66 + 2*kk];
                S4[((size_t)(b*FB + kg)*TT + t)*2 + h] = make_float4(e0.x, e0.y, e1.x, e1.y);
            }
        }
    }
}

// ---------- scan replaced by truncated exponential sum + Cholesky solve + beamform ----------
// S1/S2 layout: complex [b][f][t]
__global__ __launch_bounds__(256) void k_scan(const float* __restrict__ S, const float* __restrict__ htab,
                      float* __restrict__ S1, float* __restrict__ S2){
    int o = blockIdx.x*256 + threadIdx.x;
    if (o >= BB*FB*TT) return;
    int t  = o % TT;
    int bf = o / TT;               // b*FB + f
    int f  = bf % FB;
    const float4* Sp = (const float4*)S;
    size_t base4 = (size_t)bf*TT*2;
    float d0=0,d1=0,d2=0,d3=0;
    float2 r10={0,0}, r20={0,0}, r30={0,0}, r21={0,0}, r31={0,0}, r32={0,0};
    float2 X0={0,0}, X1={0,0}, X2={0,0}, X3={0,0};
    int tau0 = t - (KSPAN-1); if (tau0 < 0) tau0 = 0;
    float w = 0.95f;
    for (int tau = t; tau >= tau0; --tau){
        float4 v0 = Sp[base4 + (size_t)tau*2];
        float4 v1 = Sp[base4 + (size_t)tau*2 + 1];
        float2 x0 = make_float2(v0.x, v0.y), x1 = make_float2(v0.z, v0.w);
        float2 x2 = make_float2(v1.x, v1.y), x3 = make_float2(v1.z, v1.w);
        if (tau == t){ X0=x0; X1=x1; X2=x2; X3=x3; }
        float wt = (tau == 0) ? w*(1.0f/0.95f) : w;
        float y0x=wt*x0.x, y0y=wt*x0.y, y1x=wt*x1.x, y1y=wt*x1.y;
        float y2x=wt*x2.x, y2y=wt*x2.y, y3x=wt*x3.x, y3y=wt*x3.y;
        d0 += y0x*x0.x + y0y*x0.y;
        d1 += y1x*x1.x + y1y*x1.y;
        d2 += y2x*x2.x + y2y*x2.y;
        d3 += y3x*x3.x + y3y*x3.y;
        r10.x += y1x*x0.x + y1y*x0.y;  r10.y += y1y*x0.x - y1x*x0.y;
        r20.x += y2x*x0.x + y2y*x0.y;  r20.y += y2y*x0.x - y2x*x0.y;
        r30.x += y3x*x0.x + y3y*x0.y;  r30.y += y3y*x0.x - y3x*x0.y;
        r21.x += y2x*x1.x + y2y*x1.y;  r21.y += y2y*x1.x - y2x*x1.y;
        r31.x += y3x*x1.x + y3y*x1.y;  r31.y += y3y*x1.x - y3x*x1.y;
        r32.x += y3x*x2.x + y3y*x2.y;  r32.y += y3y*x2.x - y3x*x2.y;
        w *= 0.05f;
    }
    float tr  = d0 + d1 + d2 + d3;
    float lam = tr * 0.25f;
    float a00 = d0 + lam, a11 = d1 + lam, a22 = d2 + lam, a33 = d3 + lam;
    float l00 = sqrtf(a00);                       float i00 = 1.0f/l00;
    float2 L10 = cscale(r10, i00);
    float2 L20 = cscale(r20, i00);
    float2 L30 = cscale(r30, i00);
    float l11 = sqrtf(a11 - (L10.x*L10.x + L10.y*L10.y));                 float i11 = 1.0f/l11;
    float2 L21 = cscale(csub(r21, cmulcj(L20, L10)), i11);
    float2 L31 = cscale(csub(r31, cmulcj(L30, L10)), i11);
    float l22 = sqrtf(a22 - (L20.x*L20.x+L20.y*L20.y) - (L21.x*L21.x+L21.y*L21.y)); float i22 = 1.0f/l22;
    float2 L32 = cscale(csub(csub(r32, cmulcj(L30, L20)), cmulcj(L31, L21)), i22);
    float l33 = sqrtf(a33 - (L30.x*L30.x+L30.y*L30.y) - (L31.x*L31.x+L31.y*L31.y)
                          - (L32.x*L32.x+L32.y*L32.y));                   float i33 = 1.0f/l33;
    const float2* hp = (const float2*)htab;
    for (int m = 0; m < 2; ++m){
        float2 h0 = hp[(m*FB + f)*4 + 0];
        float2 h1 = hp[(m*FB + f)*4 + 1];
        float2 h2 = hp[(m*FB + f)*4 + 2];
        float2 h3 = hp[(m*FB + f)*4 + 3];
        float2 u0 = cscale(h0, i00);
        float2 u1 = cscale(csub(h1, cmulf(L10,u0)), i11);
        float2 u2 = cscale(csub(csub(h2, cmulf(L20,u0)), cmulf(L21,u1)), i22);
        float2 u3 = cscale(csub(csub(csub(h3, cmulf(L30,u0)), cmulf(L31,u1)), cmulf(L32,u2)), i33);
        float2 y3v = cscale(u3, i33);
        float2 y2v = cscale(csub(u2, cjmul(L32, y3v)), i22);
        float2 y1v = cscale(csub(csub(u1, cjmul(L21, y2v)), cjmul(L31, y3v)), i11);
        float2 y0v = cscale(csub(csub(csub(u0, cjmul(L10, y1v)), cjmul(L20, y2v)), cjmul(L30, y3v)), i00);
        float2 den = cjmul(h0, y0v), tmp;
        tmp = cjmul(h1, y1v); den.x += tmp.x; den.y += tmp.y;
        tmp = cjmul(h2, y2v); den.x += tmp.x; den.y += tmp.y;
        tmp = cjmul(h3, y3v); den.x += tmp.x; den.y += tmp.y;
        float2 num = cjmul(y0v, X0);
        tmp = cjmul(y1v, X1); num.x += tmp.x; num.y += tmp.y;
        tmp = cjmul(y2v, X2); num.x += tmp.x; num.y += tmp.y;
        tmp = cjmul(y3v, X3); num.x += tmp.x; num.y += tmp.y;
        float2 s = cdivf(num, make_float2(den.x, -den.y));
        float* dst = (m == 0) ? S1 : S2;
        ((float2*)dst)[(size_t)bf*TT + t] = s;
    }
}

// ---------- pack: S1/S2 complex [b][f][t] -> A bf16 [row=(beam*8+b)*1001+t][LDK] (hi | lo) ----------
__global__ __launch_bounds__(256) void k_pack(const float* __restrict__ S1, const float* __restrict__ S2,
                                              short* __restrict__ A){
    int tx = threadIdx.x;               // 0..63 (kk)
    int ty = threadIdx.y;               // 0..3  (row)
    int kk = blockIdx.x*64 + tx;        // 0..703
    int row = blockIdx.y*4 + ty;        // 0..16015
    if (row >= GM) return;
    int sec = (kk >= KSEC) ? 1 : 0;
    int kk2 = kk - (sec ? KSEC : 0);
    float v = 0.f;
    if (kk2 < 2*FB){
        int bin = kk2 >> 1;
        int t   = row % TT;
        int rb  = row / TT;
        int beam = rb >> 3, b = rb & 7;
        const float2* Sp = (const float2*)(beam ? S2 : S1);
        float2 s = Sp[(size_t)(b*FB + bin)*TT + t];
        v = (kk2 & 1) ? s.y : s.x;
    }
    A[(size_t)row*LDK + kk] = sec ? bf_lo(v) : bf_hi(v);
}

// ---------- Bt gen: Bt[n][LDK] bf16, irfft twiddles (fp64), hi | lo sections ----------
__global__ void k_bgen(short* __restrict__ Bt){
    int gid = blockIdx.x*256 + threadIdx.x;
    if (gid >= NFFT*LDK) return;
    int n = gid / LDK, kk = gid % LDK;
    int sec = (kk >= KSEC) ? 1 : 0;
    int kk2 = kk - (sec ? KSEC : 0);
    float v = 0.f;
    if (kk2 < 2*FB){
        int bin = kk2 >> 1;
        double c = ((bin == 0 || bin == 160) ? 1.0 : 2.0) / 320.0;
        double th = 2.0*PI_D*(double)bin*(double)n/320.0;
        double s, co; sincos(th, &s, &co);
        v = (float)((kk2 & 1) ? -c*s : c*co);
    }
    Bt[(size_t)n*LDK + kk] = sec ? bf_lo(v) : bf_hi(v);
}

// ---------- irfft MFMA GEMM: frames[GM,320] = 3-segment bf16 split product ----------
__global__ __launch_bounds__(256) void k_gemm(const short* __restrict__ A, const short* __restrict__ Bt,
                                              float* __restrict__ C){
    __shared__ short As[64*40];
    __shared__ short Bs[64*40];
    int tid = threadIdx.x;
    int row0 = blockIdx.x * 64;
    int col0 = blockIdx.y * 64;
    int wave = tid >> 6, lane = tid & 63;
    int wm = wave >> 1, wn = wave & 1;
    int l15 = lane & 15, quad = lane >> 4;
    f32x4 acc00 = {0.f,0.f,0.f,0.f}, acc01 = acc00, acc10 = acc00, acc11 = acc00;
    int tr = tid >> 2;
    int tk = (tid & 3) * 8;
    int gr = row0 + tr;
    bool rok = gr < GM;
    const size_t arow = (size_t)gr*LDK;
    const size_t brow = (size_t)(col0 + tr)*LDK;
    for (int seg = 0; seg < 3; ++seg){
        int aofs = (seg == 1) ? KSEC : 0;
        int bofs = (seg == 2) ? KSEC : 0;
        for (int kt = 0; kt < KT; ++kt){
            int k0 = kt*32;
            __syncthreads();
            bf16x8 av = {};
            if (rok) av = *(const bf16x8*)&A[arow + aofs + k0 + tk];
            bf16x8 bv = *(const bf16x8*)&Bt[brow + bofs + k0 + tk];
            *(bf16x8*)&As[tr*40 + tk] = av;
            *(bf16x8*)&Bs[tr*40 + tk] = bv;
            __syncthreads();
            bf16x8 a0 = *(bf16x8*)&As[(wm*32 + l15)*40 + quad*8];
            bf16x8 a1 = *(bf16x8*)&As[(wm*32 + 16 + l15)*40 + quad*8];
            bf16x8 b0 = *(bf16x8*)&Bs[(wn*32 + l15)*40 + quad*8];
            bf16x8 b1 = *(bf16x8*)&Bs[(wn*32 + 16 + l15)*40 + quad*8];
            acc00 = __builtin_amdgcn_mfma_f32_16x16x32_bf16(a0, b0, acc00, 0, 0, 0);
            acc01 = __builtin_amdgcn_mfma_f32_16x16x32_bf16(a0, b1, acc01, 0, 0, 0);
            acc10 = __builtin_amdgcn_mfma_f32_16x16x32_bf16(a1, b0, acc10, 0, 0, 0);
            acc11 = __builtin_amdgcn_mfma_f32_16x16x32_bf16(a1, b1, acc11, 0, 0, 0);
        }
    }
    for (int r = 0; r < 4; ++r){
        int orow0 = row0 + wm*32 + quad*4 + r;
        int ocol0 = col0 + wn*32 + l15;
        if (orow0 < GM){
            C[(size_t)orow0*NFFT + ocol0]      = acc00[r];
            C[(size_t)orow0*NFFT + ocol0 + 16] = acc01[r];
        }
        if (orow0 + 16 < GM){
            C[(size_t)(orow0+16)*NFFT + ocol0]      = acc10[r];
            C[(size_t)(orow0+16)*NFFT + ocol0 + 16] = acc11[r];
        }
    }
}

// ---------- overlap-add (wsum==2 everywhere in cropped interior) ----------
__global__ void k_ola(const float* __restrict__ frames, float* __restrict__ out){
    int gid = blockIdx.x*256 + threadIdx.x;
    if (gid >= 2*BB*LL) return;
    int o  = gid % LL;
    int rb = gid / LL;                     // beam*BB + b
    int i  = o + HOP;
    int t1 = i / HOP;
    int r  = i - t1*HOP;
    const float* fb = frames + (size_t)rb*TT*NFFT;
    float v = fb[(size_t)t1*NFFT + r] + fb[(size_t)(t1-1)*NFFT + r + HOP];
    out[gid] = v * 0.5f;
}

extern "C" void kernel_launch(void* const* d_in, const int* in_sizes, int n_in,
                              void* d_out, int out_size, void* d_ws, size_t ws_size,
                              hipStream_t stream){
    const float* in  = (const float*)d_in[0];   // [B, L, C] fp32
    const float* win = (const float*)d_in[1];   // [320] fp32
    float* ws = (float*)d_ws;
    // ws (floats): mean 32 | invmax 8 | htab 2576 | pad -> header 3072
    //              | S1 (2,578,576) | S2 (2,578,576) | S (10,314,304)   total ~62 MB
    // aliases: part -> S1[0:12288]; Bts -> shorts at S1+16384 (dead before k_scan);
    //          A_ir + Bt_ir -> S (post-scan); frames -> S1/S2 (post-pack)
    float* mean   = ws;
    float* invmax = ws + 32;
    float* htab   = ws + 48;
    float* S1     = ws + 3072;
    size_t nS1 = (size_t)2*BB*FB*TT;            // 2,578,576 floats
    float* S2 = S1 + nS1;
    float* S  = S2 + nS1;                       // 10,314,304 floats
    float* part = S1;
    short* Bts  = (short*)(S1 + 16384);         // 384*640 shorts
    short* A  = (short*)S;                      // irfft A: 16016*704 bf16
    short* Bt = (short*)(S + 5637632);          // irfft Bt: 320*704 bf16
    float* frames = S1;                         // 16016*320 floats over dead S1+S2

    k_htab<<<dim3(6), dim3(256), 0, stream>>>(htab);
    k_stats1<<<dim3(BB*RBLK), dim3(256), 0, stream>>>(in, part);
    k_stats2<<<dim3(BB), dim3(128), 0, stream>>>(part, mean, invmax);
    k_bgen_s<<<dim3((384*640 + 255)/256), dim3(256), 0, stream>>>(win, Bts);
    k_gstft<<<dim3(BB*TP*CC/64, 6), dim3(256), 0, stream>>>(in, mean, invmax, Bts, S);
    int ntup = BB*FB*TT;
    k_scan<<<dim3((ntup + 255)/256), dim3(256), 0, stream>>>(S, htab, S1, S2);
    k_bgen<<<dim3((NFFT*LDK + 255)/256), dim3(256), 0, stream>>>(Bt);
    k_pack<<<dim3(LDK/64, (GM + 3)/4), dim3(64, 4), 0, stream>>>(S1, S2, A);
    k_gemm<<<dim3((GM + 63)/64, NFFT/64), dim3(256), 0, stream>>>(A, Bt, frames);
    k_ola<<<dim3((2*BB*LL + 255)/256), dim3(256), 0, stream>>>(frames, (float*)d_out);
}